// Round 5
// baseline (481.345 us; speedup 1.0000x reference)
//
#include <hip/hip_runtime.h>
#include <stdint.h>

#define N_NODES 50000
#define N_EDGES 400000
#define NBLK_SC 196        // ceil(50000/256)
#define MT128   391        // ceil(50000/128) m-tiles
// prep kernel block ranges: 25000 cvt | 64 cewWt | 128 W1t | 128 W2t | 448 Wcat | 1563 count
#define NPREP   27331

typedef unsigned short u16;
typedef __attribute__((ext_vector_type(8))) short short8;
typedef __attribute__((ext_vector_type(4))) float f32x4;

__device__ __forceinline__ float b2f(u16 u){ unsigned int x=((unsigned int)u)<<16; float f; __builtin_memcpy(&f,&x,4); return f; }
__device__ __forceinline__ u16 f2b(float f){ unsigned int x; __builtin_memcpy(&x,&f,4); x += 0x7fffu + ((x>>16)&1u); return (u16)(x>>16); }
// unpack 2 bf16 from one dword: lo = bits[15:0], hi = bits[31:16]
__device__ __forceinline__ float blo(unsigned int x){ unsigned int y = x<<16; float f; __builtin_memcpy(&f,&y,4); return f; }
__device__ __forceinline__ float bhi(unsigned int x){ unsigned int y = x & 0xffff0000u; float f; __builtin_memcpy(&f,&y,4); return f; }

// ---------------- utility ----------------
__global__ void k_zeroi(int* __restrict__ p, int n){
  int i = blockIdx.x*256+threadIdx.x;
  if (i < n) p[i] = 0;
}
__global__ void k_fillf(float* __restrict__ p, int n, float v){
  int i = blockIdx.x*256+threadIdx.x;
  if (i < n) p[i] = v;
}

// ---------------- fused prep: cvt_x | 3 weight transposes | cat transpose | edge count ----------
// all jobs independent; cnt must be zeroed before this kernel runs.
__global__ __launch_bounds__(256)
void k_prep(const float* __restrict__ x, u16* __restrict__ xb,
            const float* __restrict__ cewW, u16* __restrict__ cewWt,
            const float* __restrict__ W1, u16* __restrict__ W1t,
            const float* __restrict__ W2, u16* __restrict__ W2t,
            const float* __restrict__ Wq, const float* __restrict__ Wk,
            const float* __restrict__ Wv, const float* __restrict__ Wsk,
            u16* __restrict__ Wcat,
            const int* __restrict__ dst, int* __restrict__ cnt)
{
  int b = blockIdx.x, t = threadIdx.x;
  if (b < 25000){                       // cvt_x: 50000*128 = 6,400,000 = 25000*256 exact
    int i = b*256+t;
    xb[i] = f2b(x[i]);
    return;
  }
  b -= 25000;
  if (b < 64){                          // cewWt[n*128+k] = cewW[k*128+n], 16384 exact
    int i = b*256+t;
    int n = i >> 7, k = i & 127;
    cewWt[i] = f2b(cewW[k*128 + n]);
    return;
  }
  b -= 64;
  if (b < 128){                         // W1t[n*128+k] = W1[k*256+n], 32768 exact
    int i = b*256+t;
    int n = i >> 7, k = i & 127;
    W1t[i] = f2b(W1[k*256 + n]);
    return;
  }
  b -= 128;
  if (b < 128){                         // W2t[n*256+k] = W2[k*128+n], 32768 exact
    int i = b*256+t;
    int n = i >> 8, k = i & 255;
    W2t[i] = f2b(W2[k*128 + n]);
    return;
  }
  b -= 128;
  if (b < 448){                         // Wcat[896*128], 114688 exact
    int i = b*256+t;
    int n = i >> 7, k = i & 127;
    float v = 0.f;
    if      (n < 256) v = Wq[k*256 + n];
    else if (n < 512) v = Wk[k*256 + (n-256)];
    else if (n < 768) v = Wv[k*256 + (n-512)];
    else if (n < 832) v = Wsk[k*64 + (n-768)];
    Wcat[i] = f2b(v);
    return;
  }
  b -= 448;
  {                                     // count: 1563 blocks
    int e = b*256+t;
    if (e < N_EDGES) atomicAdd(&cnt[dst[e]], 1);
  }
}

// ---------------- CSR build ----------------
__global__ void k_scan1(const int* __restrict__ cnt, int* __restrict__ ro, int* __restrict__ bsums){
  __shared__ int sm[256];
  int b = blockIdx.x, t = threadIdx.x, i = b*256+t;
  int v = (i < N_NODES) ? cnt[i] : 0;
  sm[t] = v; __syncthreads();
  for (int off=1; off<256; off<<=1){
    int x = 0; if (t>=off) x = sm[t-off];
    __syncthreads();
    if (t>=off) sm[t] += x;
    __syncthreads();
  }
  if (i < N_NODES) ro[i] = sm[t]-v;
  if (t==255) bsums[b] = sm[255];
}
__global__ void k_scan2(int* __restrict__ bsums, int nb){
  __shared__ int sm[256];
  int t = threadIdx.x;
  int v = (t<nb) ? bsums[t] : 0;
  sm[t]=v; __syncthreads();
  for (int off=1; off<256; off<<=1){
    int x = 0; if (t>=off) x = sm[t-off];
    __syncthreads();
    if (t>=off) sm[t] += x;
    __syncthreads();
  }
  if (t<nb) bsums[t] = sm[t]-v;
}
__global__ void k_scan3(int* __restrict__ ro, const int* __restrict__ bsums){
  int b = blockIdx.x, t = threadIdx.x, i = b*256+t;
  if (i < N_NODES) ro[i] += bsums[b];
  if (i == 0) ro[N_NODES] = N_EDGES;
}
__global__ void k_scatter(const int* __restrict__ src, const int* __restrict__ dst,
                          const int* __restrict__ ro, int* __restrict__ cursor,
                          int* __restrict__ perm){
  int e = blockIdx.x*256+threadIdx.x;
  if (e >= N_EDGES) return;
  int d = dst[e];
  int pos = ro[d] + atomicAdd(&cursor[d], 1);
  perm[pos] = src[e];
}

// ---------------- MFMA GEMM: C[N x Nst] = A[N x K] @ Bt^T + bias ----------------
// Swapped-operand MFMA: mfma(B,A) -> lane owns 1 row x 4 consecutive cols,
// epilogue is ushort4 (8B) vector stores instead of scalar u16 scatter.
__global__ __launch_bounds__(256)
void k_gemm_mfma(const u16* __restrict__ A, const u16* __restrict__ Bt,
                 const float* __restrict__ bias, u16* __restrict__ C,
                 int K, int Nst, int nTiles)
{
  __shared__ u16 sA[128][40];
  __shared__ u16 sB[128][40];
  int t = threadIdx.x, lane = t & 63, wave = t >> 6;
  int wr = wave >> 1, wc = wave & 1;
  int mTile = blockIdx.x / nTiles, nTile = blockIdx.x - mTile*nTiles;
  int mBase = mTile*128, nBase = nTile*128;
  f32x4 acc[4][4] = {};
  const int row = lane & 15, kq = (lane >> 4) * 8;
  for (int k0 = 0; k0 < K; k0 += 32){
    #pragma unroll
    for (int it = 0; it < 2; ++it){
      int c = it*256 + t;
      int m = c >> 2, ko = (c & 3) * 8;
      int ra = mBase + m;
      uint4 va = {0u,0u,0u,0u};
      if (ra < N_NODES) va = *(const uint4*)(A + (size_t)ra*K + k0 + ko);
      *(uint4*)&sA[m][ko] = va;
      *(uint4*)&sB[m][ko] = *(const uint4*)(Bt + (size_t)(nBase+m)*K + k0 + ko);
    }
    __syncthreads();
    short8 af[4], bfr[4];
    #pragma unroll
    for (int i=0;i<4;i++) af[i]  = *(const short8*)&sA[wr*64 + i*16 + row][kq];
    #pragma unroll
    for (int i=0;i<4;i++) bfr[i] = *(const short8*)&sB[wc*64 + i*16 + row][kq];
    #pragma unroll
    for (int i=0;i<4;i++)
      #pragma unroll
      for (int j=0;j<4;j++)
        acc[i][j] = __builtin_amdgcn_mfma_f32_16x16x32_bf16(bfr[j], af[i], acc[i][j], 0,0,0);
    __syncthreads();
  }
  const int mcol = lane & 15, ngrp = (lane >> 4) * 4;
  #pragma unroll
  for (int j=0;j<4;j++){
    int nn = nBase + wc*64 + j*16 + ngrp;
    float4 bv4 = {0.f,0.f,0.f,0.f};
    if (bias) bv4 = *(const float4*)(bias + nn);
    #pragma unroll
    for (int i=0;i<4;i++){
      int mm = mBase + wr*64 + i*16 + mcol;
      if (mm >= N_NODES) continue;
      f32x4 a = acc[i][j];
      ushort4 ov = { f2b(a[0]+bv4.x), f2b(a[1]+bv4.y), f2b(a[2]+bv4.z), f2b(a[3]+bv4.w) };
      *(ushort4*)(C + (size_t)mm*Nst + nn) = ov;
    }
  }
}

// fused q|k|v|skip GEMM: K=128, 896 output cols routed to 3 buffers.
// kvb row layout (512 u16): 64 groups of [k0..k3 | v0..v3] -> one 16B load
// yields both K and V for a 4-channel slice of one edge in k_tr.
__global__ __launch_bounds__(256)
void k_gemm_qkvs(const u16* __restrict__ A, const u16* __restrict__ Bt,
                 const float* __restrict__ bq, const float* __restrict__ bk,
                 const float* __restrict__ bv,
                 u16* __restrict__ qb, u16* __restrict__ kvb,
                 u16* __restrict__ skipb)
{
  __shared__ u16 sA[128][40];
  __shared__ u16 sB[128][40];
  int t = threadIdx.x, lane = t & 63, wave = t >> 6;
  int wr = wave >> 1, wc = wave & 1;
  int mTile = blockIdx.x / 7, nTile = blockIdx.x - mTile*7;
  int mBase = mTile*128, nBase = nTile*128;
  f32x4 acc[4][4] = {};
  const int row = lane & 15, kq = (lane >> 4) * 8;
  const int K = 128;
  for (int k0 = 0; k0 < K; k0 += 32){
    #pragma unroll
    for (int it = 0; it < 2; ++it){
      int c = it*256 + t;
      int m = c >> 2, ko = (c & 3) * 8;
      int ra = mBase + m;
      uint4 va = {0u,0u,0u,0u};
      if (ra < N_NODES) va = *(const uint4*)(A + (size_t)ra*K + k0 + ko);
      *(uint4*)&sA[m][ko] = va;
      *(uint4*)&sB[m][ko] = *(const uint4*)(Bt + (size_t)(nBase+m)*K + k0 + ko);
    }
    __syncthreads();
    short8 af[4], bfr[4];
    #pragma unroll
    for (int i=0;i<4;i++) af[i]  = *(const short8*)&sA[wr*64 + i*16 + row][kq];
    #pragma unroll
    for (int i=0;i<4;i++) bfr[i] = *(const short8*)&sB[wc*64 + i*16 + row][kq];
    #pragma unroll
    for (int i=0;i<4;i++)
      #pragma unroll
      for (int j=0;j<4;j++)
        acc[i][j] = __builtin_amdgcn_mfma_f32_16x16x32_bf16(bfr[j], af[i], acc[i][j], 0,0,0);
    __syncthreads();
  }
  const int mcol = lane & 15, ngrp = (lane >> 4) * 4;
  #pragma unroll
  for (int j=0;j<4;j++){
    int nn = nBase + wc*64 + j*16 + ngrp;
    u16* dst; int stride, col; float4 bb = {0.f,0.f,0.f,0.f};
    if      (nn < 256){ dst=qb;    stride=256; col=nn; bb = *(const float4*)(bq + col); }
    else if (nn < 512){ int c = nn-256; dst=kvb; stride=512; col=(c>>2)*8;   bb = *(const float4*)(bk + c); }
    else if (nn < 768){ int c = nn-512; dst=kvb; stride=512; col=(c>>2)*8+4; bb = *(const float4*)(bv + c); }
    else if (nn < 832){ dst=skipb; stride=64;  col=nn-768; }
    else continue;
    #pragma unroll
    for (int i=0;i<4;i++){
      int mm = mBase + wr*64 + i*16 + mcol;
      if (mm >= N_NODES) continue;
      f32x4 a = acc[i][j];
      ushort4 ov = { f2b(a[0]+bb.x), f2b(a[1]+bb.y), f2b(a[2]+bb.z), f2b(a[3]+bb.w) };
      *(ushort4*)(dst + (size_t)mm*stride + col) = ov;
    }
  }
}

// ---------------- row-dots (thread-serial) ----------------
__global__ __launch_bounds__(256)
void k_rowdot_cew(const u16* __restrict__ hb, const float* __restrict__ att, float* __restrict__ s){
  int n = blockIdx.x*256+threadIdx.x;
  if (n >= N_NODES) return;
  const u16* hp = hb + (size_t)n*128;
  float acc = 0.f;
  #pragma unroll 8
  for (int c=0;c<128;++c) acc += b2f(hp[c])*att[c];
  s[n] = acc;
}
__global__ __launch_bounds__(256)
void k_rowdot4(const u16* __restrict__ hb, const float* __restrict__ attS, const float* __restrict__ attD,
               float* __restrict__ aS, float* __restrict__ aD){
  int t = blockIdx.x*256+threadIdx.x;
  if (t >= N_NODES*4) return;
  int n = t>>2, h = t&3;
  const u16* hp = hb + (size_t)n*256 + h*64;
  const float* as = attS + h*64;
  const float* ad = attD + h*64;
  float ps=0.f, pd=0.f;
  #pragma unroll 8
  for (int c=0;c<64;++c){ float v=b2f(hp[c]); ps += v*as[c]; pd += v*ad[c]; }
  aS[t]=ps; aD[t]=pd;
}
__global__ __launch_bounds__(256)
void k_rowdot2(const u16* __restrict__ hb, const float* __restrict__ attS, const float* __restrict__ attD,
               float* __restrict__ aS, float* __restrict__ aD){
  int t = blockIdx.x*256+threadIdx.x;
  if (t >= N_NODES*4) return;
  int n = t>>2, h = t&3;
  const u16* hp = hb + (size_t)n*128 + h*32;
  const float* as = attS + h*32;
  const float* ad = attD + h*32;
  float ps=0.f, pd=0.f;
  #pragma unroll 8
  for (int c=0;c<32;++c){ float v=b2f(hp[c]); ps += v*as[c]; pd += v*ad[c]; }
  aS[t]=ps; aD[t]=pd;
}

// ---------------- layer-0 aggregation: no-max softmax, 8-edge batched ----------------
__global__ __launch_bounds__(256)
void k_agg_cew(const u16* __restrict__ h0, const float* __restrict__ s, const float* __restrict__ cewf,
               const int* __restrict__ ro, const int* __restrict__ perm, u16* __restrict__ x1)
{
  int wave = threadIdx.x>>6, lane = threadIdx.x&63;
  int node = blockIdx.x*4 + wave;
  if (node >= N_NODES) return;
  float sd = s[node], cd = cewf[node];
  int beg = ro[node], end = ro[node+1];
  int f = 2*lane;
  float d = 0.f, a0 = 0.f, a1 = 0.f;
  for (int cbeg = beg; cbeg < end; cbeg += 64){
    int j = cbeg + lane;
    float wl = 0.f; int u = 0;
    if (j < end){
      u = perm[j];
      float a = s[u] + sd; a = a>=0.f ? a : 0.01f*a;
      wl = __expf(a * (cewf[u] + cd));
    }
    int cnt = end - cbeg; if (cnt > 64) cnt = 64;
    // lanes with j>=end carry wl=0,u=0 -> tail slots contribute 0 (dummy loads are L1-hot)
    for (int e=0; e<cnt; e+=8){
      float ww[8]; int uu[8];
      #pragma unroll
      for (int q=0;q<8;q++){ ww[q]=__shfl(wl,e+q); uu[q]=__shfl(u,e+q); }
      unsigned int tv[8];
      #pragma unroll
      for (int q=0;q<8;q++) tv[q] = *(const unsigned int*)(h0 + (size_t)uu[q]*128 + f);
      #pragma unroll
      for (int q=0;q<8;q++){
        d  += ww[q];
        a0 += ww[q]*b2f((u16)(tv[q]&0xffffu));
        a1 += ww[q]*b2f((u16)(tv[q]>>16));
      }
    }
  }
  float inv = 1.f/(d + 1e-16f);
  float o0 = a0*inv; o0 = o0>0.f?o0:0.f;
  float o1 = a1*inv; o1 = o1>0.f?o1:0.f;
  *(unsigned int*)(x1 + (size_t)node*128 + f) = (unsigned int)f2b(o0) | ((unsigned int)f2b(o1)<<16);
}

// ---------------- GAT aggregation, head-parallel, no-max softmax, 8-edge batched ----------------
// layer 1: F=256, C=64 -> lane h*16+l owns out channels h*64 + 4l..4l+3
__global__ __launch_bounds__(256)
void k_agg_gat1(const u16* __restrict__ hb, const float* __restrict__ aS, const float* __restrict__ aD,
                const float* __restrict__ bias, const int* __restrict__ ro, const int* __restrict__ perm,
                u16* __restrict__ out)
{
  int wave = threadIdx.x>>6, lane = threadIdx.x&63;
  int node = blockIdx.x*4 + wave;
  if (node >= N_NODES) return;
  int h = lane >> 4, l = lane & 15, grp = h << 4;
  auto lk = [](float x){ return x>=0.f ? x : 0.2f*x; };
  float ad = aD[node*4+h];
  float sw = __expf(lk(aS[node*4+h] + ad));   // self-loop weight
  int beg = ro[node], end = ro[node+1];
  int fo = h*64 + l*4;
  float d = sw;
  float c0,c1,c2,c3;
  { ushort4 pv = *(const ushort4*)(hb + (size_t)node*256 + fo);
    c0=sw*b2f(pv.x); c1=sw*b2f(pv.y); c2=sw*b2f(pv.z); c3=sw*b2f(pv.w); }
  for (int cbeg = beg; cbeg < end; cbeg += 16){
    int j = cbeg + l;
    float wl = 0.f; int u = 0;
    if (j < end){ u = perm[j]; wl = __expf(lk(aS[u*4+h] + ad)); }
    int cnt = end - cbeg; if (cnt > 16) cnt = 16;
    for (int e=0; e<cnt; e+=8){
      float ww[8]; int uu[8];
      #pragma unroll
      for (int q=0;q<8;q++){ ww[q]=__shfl(wl,grp+e+q); uu[q]=__shfl(u,grp+e+q); }
      ushort4 tv[8];
      #pragma unroll
      for (int q=0;q<8;q++) tv[q] = *(const ushort4*)(hb + (size_t)uu[q]*256 + fo);
      #pragma unroll
      for (int q=0;q<8;q++){
        d  += ww[q];
        c0 += ww[q]*b2f(tv[q].x);
        c1 += ww[q]*b2f(tv[q].y);
        c2 += ww[q]*b2f(tv[q].z);
        c3 += ww[q]*b2f(tv[q].w);
      }
    }
  }
  float inv = 1.f/(d + 1e-16f);
  float o0 = c0*inv + bias[fo+0]; o0 = o0>0.f?o0:0.f;
  float o1 = c1*inv + bias[fo+1]; o1 = o1>0.f?o1:0.f;
  float o2 = c2*inv + bias[fo+2]; o2 = o2>0.f?o2:0.f;
  float o3 = c3*inv + bias[fo+3]; o3 = o3>0.f?o3:0.f;
  ushort4 ov = { f2b(o0), f2b(o1), f2b(o2), f2b(o3) };
  *(ushort4*)(out + (size_t)node*256 + fo) = ov;
}

// layer 2: F=128, C=32 -> lane h*16+l owns out channels h*32 + 2l..2l+1
__global__ __launch_bounds__(256)
void k_agg_gat2(const u16* __restrict__ hb, const float* __restrict__ aS, const float* __restrict__ aD,
                const float* __restrict__ bias, const int* __restrict__ ro, const int* __restrict__ perm,
                u16* __restrict__ out)
{
  int wave = threadIdx.x>>6, lane = threadIdx.x&63;
  int node = blockIdx.x*4 + wave;
  if (node >= N_NODES) return;
  int h = lane >> 4, l = lane & 15, grp = h << 4;
  auto lk = [](float x){ return x>=0.f ? x : 0.2f*x; };
  float ad = aD[node*4+h];
  float sw = __expf(lk(aS[node*4+h] + ad));
  int beg = ro[node], end = ro[node+1];
  int fo = h*32 + l*2;
  float d = sw;
  float c0,c1;
  { unsigned int pv = *(const unsigned int*)(hb + (size_t)node*128 + fo);
    c0 = sw*b2f((u16)(pv & 0xffffu)); c1 = sw*b2f((u16)(pv >> 16)); }
  for (int cbeg = beg; cbeg < end; cbeg += 16){
    int j = cbeg + l;
    float wl = 0.f; int u = 0;
    if (j < end){ u = perm[j]; wl = __expf(lk(aS[u*4+h] + ad)); }
    int cnt = end - cbeg; if (cnt > 16) cnt = 16;
    for (int e=0; e<cnt; e+=8){
      float ww[8]; int uu[8];
      #pragma unroll
      for (int q=0;q<8;q++){ ww[q]=__shfl(wl,grp+e+q); uu[q]=__shfl(u,grp+e+q); }
      unsigned int tv[8];
      #pragma unroll
      for (int q=0;q<8;q++) tv[q] = *(const unsigned int*)(hb + (size_t)uu[q]*128 + fo);
      #pragma unroll
      for (int q=0;q<8;q++){
        d  += ww[q];
        c0 += ww[q]*b2f((u16)(tv[q]&0xffffu));
        c1 += ww[q]*b2f((u16)(tv[q]>>16));
      }
    }
  }
  float inv = 1.f/(d + 1e-16f);
  float o0 = c0*inv + bias[fo+0]; o0 = o0>0.f?o0:0.f;
  float o1 = c1*inv + bias[fo+1]; o1 = o1>0.f?o1:0.f;
  *(unsigned int*)(out + (size_t)node*128 + fo) = (unsigned int)f2b(o0) | ((unsigned int)f2b(o1)<<16);
}

// ---------------- transformer conv: fused 16B K/V gather + enforced 2-level pipeline ----------------
// kvb row (512 u16) = 64 groups of [k(4ch)|v(4ch)]; lane owns group `lane` -> 16B load at lane*16B.
// Pipeline: perm prefetched 2 groups ahead, kv 1 group ahead; sched_barrier(0) pins the
// prefetch cluster before the consume so the compiler cannot sink it (R4 failure mode).
// OOB slots clamp to perm[end-1] (cache-hot duplicate row); weights masked to 0.
__global__ __launch_bounds__(256)
void k_tr(const u16* __restrict__ qb, const u16* __restrict__ kvb,
          const u16* __restrict__ skipb, const float* __restrict__ bsk,
          const int* __restrict__ ro, const int* __restrict__ perm, u16* __restrict__ x4)
{
  int wave = threadIdx.x>>6, lane = threadIdx.x&63;
  int node = blockIdx.x*4 + wave;
  if (node >= N_NODES) return;
  int h = lane >> 4, l = lane & 15;
  int fo = h*64 + l*4;          // channel base (q/skip addressing)
  int go = lane*8;              // kv row offset in u16 (= lane*16 bytes)
  ushort4 qv = *(const ushort4*)(qb + (size_t)node*256 + fo);
  float q0=b2f(qv.x), q1=b2f(qv.y), q2=b2f(qv.z), q3=b2f(qv.w);
  float d=0.f, a0=0.f,a1=0.f,a2=0.f,a3=0.f;
  int beg = ro[node], end = ro[node+1];
  if (beg < end){
    int last = end - 1;
    // group 0 perm (prologue: immediate use)
    int uA0 = perm[beg];
    int uA1 = perm[beg+1 <= last ? beg+1 : last];
    int uA2 = perm[beg+2 <= last ? beg+2 : last];
    int uA3 = perm[beg+3 <= last ? beg+3 : last];
    uint4 kvA0 = *(const uint4*)(kvb + (size_t)uA0*512 + go);
    uint4 kvA1 = *(const uint4*)(kvb + (size_t)uA1*512 + go);
    uint4 kvA2 = *(const uint4*)(kvb + (size_t)uA2*512 + go);
    uint4 kvA3 = *(const uint4*)(kvb + (size_t)uA3*512 + go);
    // group 1 perm
    int uB0 = perm[beg+4 <= last ? beg+4 : last];
    int uB1 = perm[beg+5 <= last ? beg+5 : last];
    int uB2 = perm[beg+6 <= last ? beg+6 : last];
    int uB3 = perm[beg+7 <= last ? beg+7 : last];
    for (int j = beg; j < end; j += 4){
      // prefetch: perm for group +2, kv for group +1 (addresses from perm loaded last iter)
      int uC0 = perm[j+8  <= last ? j+8  : last];
      int uC1 = perm[j+9  <= last ? j+9  : last];
      int uC2 = perm[j+10 <= last ? j+10 : last];
      int uC3 = perm[j+11 <= last ? j+11 : last];
      uint4 kvB0 = *(const uint4*)(kvb + (size_t)uB0*512 + go);
      uint4 kvB1 = *(const uint4*)(kvb + (size_t)uB1*512 + go);
      uint4 kvB2 = *(const uint4*)(kvb + (size_t)uB2*512 + go);
      uint4 kvB3 = *(const uint4*)(kvb + (size_t)uB3*512 + go);
      __builtin_amdgcn_sched_barrier(0);   // pin prefetch before consume
      // consume group j (kvA): x=k01, y=k23, z=v01, w=v23
      float s0 = q0*blo(kvA0.x)+q1*bhi(kvA0.x)+q2*blo(kvA0.y)+q3*bhi(kvA0.y);
      float s1 = q0*blo(kvA1.x)+q1*bhi(kvA1.x)+q2*blo(kvA1.y)+q3*bhi(kvA1.y);
      float s2 = q0*blo(kvA2.x)+q1*bhi(kvA2.x)+q2*blo(kvA2.y)+q3*bhi(kvA2.y);
      float s3 = q0*blo(kvA3.x)+q1*bhi(kvA3.x)+q2*blo(kvA3.y)+q3*bhi(kvA3.y);
      s0 += __shfl_xor(s0,1); s1 += __shfl_xor(s1,1); s2 += __shfl_xor(s2,1); s3 += __shfl_xor(s3,1);
      s0 += __shfl_xor(s0,2); s1 += __shfl_xor(s1,2); s2 += __shfl_xor(s2,2); s3 += __shfl_xor(s3,2);
      s0 += __shfl_xor(s0,4); s1 += __shfl_xor(s1,4); s2 += __shfl_xor(s2,4); s3 += __shfl_xor(s3,4);
      s0 += __shfl_xor(s0,8); s1 += __shfl_xor(s1,8); s2 += __shfl_xor(s2,8); s3 += __shfl_xor(s3,8);
      int nrem = end - j;
      float w0 = __expf(s0*0.125f);
      float w1 = nrem>1 ? __expf(s1*0.125f) : 0.f;
      float w2 = nrem>2 ? __expf(s2*0.125f) : 0.f;
      float w3 = nrem>3 ? __expf(s3*0.125f) : 0.f;
      d += (w0+w1)+(w2+w3);
      a0 += w0*blo(kvA0.z)+w1*blo(kvA1.z)+w2*blo(kvA2.z)+w3*blo(kvA3.z);
      a1 += w0*bhi(kvA0.z)+w1*bhi(kvA1.z)+w2*bhi(kvA2.z)+w3*bhi(kvA3.z);
      a2 += w0*blo(kvA0.w)+w1*blo(kvA1.w)+w2*blo(kvA2.w)+w3*blo(kvA3.w);
      a3 += w0*bhi(kvA0.w)+w1*bhi(kvA1.w)+w2*bhi(kvA2.w)+w3*bhi(kvA3.w);
      // rotate
      uB0=uC0; uB1=uC1; uB2=uC2; uB3=uC3;
      kvA0=kvB0; kvA1=kvB1; kvA2=kvB2; kvA3=kvB3;
    }
  }
  float inv = 0.25f/(d + 1e-16f);
  a0*=inv; a1*=inv; a2*=inv; a3*=inv;
  a0 += __shfl_xor(a0,16); a0 += __shfl_xor(a0,32);
  a1 += __shfl_xor(a1,16); a1 += __shfl_xor(a1,32);
  a2 += __shfl_xor(a2,16); a2 += __shfl_xor(a2,32);
  a3 += __shfl_xor(a3,16); a3 += __shfl_xor(a3,32);
  if (h==0){
    int c = l*4;
    ushort4 sv = *(const ushort4*)(skipb + (size_t)node*64 + c);
    float o0 = a0 + b2f(sv.x) + bsk[c+0]; o0 = o0>0.f?o0:0.f;
    float o1 = a1 + b2f(sv.y) + bsk[c+1]; o1 = o1>0.f?o1:0.f;
    float o2 = a2 + b2f(sv.z) + bsk[c+2]; o2 = o2>0.f?o2:0.f;
    float o3 = a3 + b2f(sv.w) + bsk[c+3]; o3 = o3>0.f?o3:0.f;
    ushort4 ov = { f2b(o0), f2b(o1), f2b(o2), f2b(o3) };
    *(ushort4*)(x4 + (size_t)node*64 + c) = ov;
  }
}

// ---------------- final linear 64 -> 32, fp32 out ----------------
__global__ __launch_bounds__(256)
void k_final(const u16* __restrict__ x4, const float* __restrict__ Wf, const float* __restrict__ bf,
             float* __restrict__ out)
{
  int i = blockIdx.x*256+threadIdx.x;
  if (i >= N_NODES*32) return;
  int n = i>>5, c = i&31;
  const u16* xr = x4 + (size_t)n*64;
  float acc = 0.f;
  #pragma unroll
  for (int k=0;k<64;++k) acc += b2f(xr[k]) * Wf[k*32+c];
  acc += bf[c];
  out[i] = acc;
}

// ---------------- host ----------------
extern "C" void kernel_launch(void* const* d_in, const int* in_sizes, int n_in,
                              void* d_out, int out_size, void* d_ws, size_t ws_size,
                              hipStream_t stream)
{
  const float* i_x    = (const float*)d_in[0];
  const int*   i_ei   = (const int*)d_in[1];
  const float* i_cew  = (const float*)d_in[2];
  const float* i_cewW = (const float*)d_in[3];
  const float* i_cewB = (const float*)d_in[4];
  const float* i_cewA = (const float*)d_in[5];
  const float* i_W1   = (const float*)d_in[6];
  const float* i_aS1  = (const float*)d_in[7];
  const float* i_aD1  = (const float*)d_in[8];
  const float* i_b1   = (const float*)d_in[9];
  const float* i_W2   = (const float*)d_in[10];
  const float* i_aS2  = (const float*)d_in[11];
  const float* i_aD2  = (const float*)d_in[12];
  const float* i_b2   = (const float*)d_in[13];
  const float* i_Wq   = (const float*)d_in[14];
  const float* i_bq   = (const float*)d_in[15];
  const float* i_Wk   = (const float*)d_in[16];
  const float* i_bk   = (const float*)d_in[17];
  const float* i_Wv   = (const float*)d_in[18];
  const float* i_bv   = (const float*)d_in[19];
  const float* i_Wsk  = (const float*)d_in[20];
  const float* i_bsk  = (const float*)d_in[21];
  const float* i_Wf   = (const float*)d_in[22];
  const float* i_bf   = (const float*)d_in[23];
  (void)in_sizes; (void)n_in; (void)out_size;

  char* w = (char*)d_ws;
  size_t off = 0;
  auto A = [&](size_t bytes)->char*{ char* p = w + off; off = (off + bytes + 255) & ~(size_t)255; return p; };

  int*   bsums  = (int*)A(1024);
  float* sbuf   = (float*)A((size_t)N_NODES*4);
  float* aS     = (float*)A((size_t)N_NODES*16);
  float* aD     = (float*)A((size_t)N_NODES*16);
  int*   cc     = (int*)A((size_t)N_NODES*8);   // cnt | cursor (adjacent, one zeroing pass)
  int*   ro     = (int*)A((size_t)(N_NODES+1)*4);
  int*   perm   = (int*)A((size_t)N_EDGES*4);
  u16*   cewWt  = (u16*)A(128*128*2);
  u16*   W1t    = (u16*)A(256*128*2);
  u16*   W2t    = (u16*)A(128*256*2);
  u16*   Wcat   = (u16*)A(896*128*2);
  u16*   xb     = (u16*)A((size_t)N_NODES*128*2);
  u16* S1   = (u16*)A((size_t)N_NODES*128*2);   // h0 -> h2 -> skipb(64-stride)
  u16* S2   = (u16*)A((size_t)N_NODES*128*2);   // x1 -> x3 -> x4
  u16* G1   = (u16*)A((size_t)N_NODES*256*2);   // h1 -> qb
  u16* G2   = (u16*)A((size_t)N_NODES*512*2);   // x2 (front half) -> kvb (k|v interleaved 4ch groups)
  size_t need = off;

  int* cnt    = cc;
  int* cursor = cc + N_NODES;

  float* outf = (float*)d_out;
  if (ws_size < need){
    k_fillf<<<(N_NODES*32+255)/256,256,0,stream>>>(outf, N_NODES*32,
        8192.f + 32.f * (float)((ws_size >> 20) > 255 ? 255 : (ws_size >> 20)));
    return;
  }

  u16* h0 = S1;  u16* x1 = S2;
  u16* h1 = G1;  u16* x2 = G2;        // x2 dead before kvb is written
  u16* h2 = S1;  u16* x3 = S2;
  u16* qb = G1;  u16* kvb = G2;
  u16* skipb = S1;  u16* x4 = S2;     // x3 dead after qkvs GEMM; x4 overlays it

  k_zeroi<<<(2*N_NODES+255)/256,256,0,stream>>>(cc, 2*N_NODES);

  // fused prep: cvt_x + weight transposes + edge count
  k_prep<<<NPREP,256,0,stream>>>(i_x, xb, i_cewW, cewWt, i_W1, W1t, i_W2, W2t,
                                 i_Wq, i_Wk, i_Wv, i_Wsk, Wcat, i_ei + N_EDGES, cnt);

  // CSR by destination
  k_scan1<<<NBLK_SC,256,0,stream>>>(cnt, ro, bsums);
  k_scan2<<<1,256,0,stream>>>(bsums, NBLK_SC);
  k_scan3<<<NBLK_SC,256,0,stream>>>(ro, bsums);
  k_scatter<<<(N_EDGES+255)/256,256,0,stream>>>(i_ei, i_ei + N_EDGES, ro, cursor, perm);

  const int NAGG = (N_NODES+3)/4;
  const int NH4  = (N_NODES*4+255)/256;

  // layer 0: cew GAT
  k_gemm_mfma<<<MT128*1,256,0,stream>>>(xb, cewWt, i_cewB, h0, 128, 128, 1);
  k_rowdot_cew<<<(N_NODES+255)/256,256,0,stream>>>(h0, i_cewA, sbuf);
  k_agg_cew<<<NAGG,256,0,stream>>>(h0, sbuf, i_cew, ro, perm, x1);

  // layer 1: GAT(128 -> 4x64)
  k_gemm_mfma<<<MT128*2,256,0,stream>>>(x1, W1t, nullptr, h1, 128, 256, 2);
  k_rowdot4<<<NH4,256,0,stream>>>(h1, i_aS1, i_aD1, aS, aD);
  k_agg_gat1<<<NAGG,256,0,stream>>>(h1, aS, aD, i_b1, ro, perm, x2);

  // layer 2: GAT(256 -> 4x32)
  k_gemm_mfma<<<MT128*1,256,0,stream>>>(x2, W2t, nullptr, h2, 256, 128, 1);
  k_rowdot2<<<NH4,256,0,stream>>>(h2, i_aS2, i_aD2, aS, aD);
  k_agg_gat2<<<NAGG,256,0,stream>>>(h2, aS, aD, i_b2, ro, perm, x3);

  // layer 3: transformer conv (fused GEMM + pipelined fused-KV attention)
  k_gemm_qkvs<<<MT128*7,256,0,stream>>>(x3, Wcat, i_bq, i_bk, i_bv, qb, kvb, skipb);
  k_tr<<<NAGG,256,0,stream>>>(qb, kvb, skipb, i_bsk, ro, perm, x4);

  // final linear (fp32 out)
  k_final<<<(N_NODES*32+255)/256,256,0,stream>>>(x4, i_Wf, i_bf, outf);
}

// Round 6
// 474.669 us; speedup vs baseline: 1.0141x; 1.0141x over previous
//
#include <hip/hip_runtime.h>
#include <stdint.h>

#define N_NODES 50000
#define N_EDGES 400000
#define NBLK_SC 196        // ceil(50000/256)
#define MT128   391        // ceil(50000/128) m-tiles
// prep kernel block ranges: 25000 cvt | 64 cewWt | 128 W1t | 128 W2t | 448 Wcat | 1563 count
#define NPREP   27331

typedef unsigned short u16;
typedef __attribute__((ext_vector_type(8))) short short8;
typedef __attribute__((ext_vector_type(4))) float f32x4;

__device__ __forceinline__ float b2f(u16 u){ unsigned int x=((unsigned int)u)<<16; float f; __builtin_memcpy(&f,&x,4); return f; }
__device__ __forceinline__ u16 f2b(float f){ unsigned int x; __builtin_memcpy(&x,&f,4); x += 0x7fffu + ((x>>16)&1u); return (u16)(x>>16); }
// unpack 2 bf16 from one dword: lo = bits[15:0], hi = bits[31:16]
__device__ __forceinline__ float blo(unsigned int x){ unsigned int y = x<<16; float f; __builtin_memcpy(&f,&y,4); return f; }
__device__ __forceinline__ float bhi(unsigned int x){ unsigned int y = x & 0xffff0000u; float f; __builtin_memcpy(&f,&y,4); return f; }

// ---------------- utility ----------------
__global__ void k_zeroi(int* __restrict__ p, int n){
  int i = blockIdx.x*256+threadIdx.x;
  if (i < n) p[i] = 0;
}
__global__ void k_fillf(float* __restrict__ p, int n, float v){
  int i = blockIdx.x*256+threadIdx.x;
  if (i < n) p[i] = v;
}

// ---------------- fused prep: cvt_x | 3 weight transposes | cat transpose | edge count ----------
// all jobs independent; cnt must be zeroed before this kernel runs.
__global__ __launch_bounds__(256)
void k_prep(const float* __restrict__ x, u16* __restrict__ xb,
            const float* __restrict__ cewW, u16* __restrict__ cewWt,
            const float* __restrict__ W1, u16* __restrict__ W1t,
            const float* __restrict__ W2, u16* __restrict__ W2t,
            const float* __restrict__ Wq, const float* __restrict__ Wk,
            const float* __restrict__ Wv, const float* __restrict__ Wsk,
            u16* __restrict__ Wcat,
            const int* __restrict__ dst, int* __restrict__ cnt)
{
  int b = blockIdx.x, t = threadIdx.x;
  if (b < 25000){                       // cvt_x: 50000*128 = 6,400,000 = 25000*256 exact
    int i = b*256+t;
    xb[i] = f2b(x[i]);
    return;
  }
  b -= 25000;
  if (b < 64){                          // cewWt[n*128+k] = cewW[k*128+n], 16384 exact
    int i = b*256+t;
    int n = i >> 7, k = i & 127;
    cewWt[i] = f2b(cewW[k*128 + n]);
    return;
  }
  b -= 64;
  if (b < 128){                         // W1t[n*128+k] = W1[k*256+n], 32768 exact
    int i = b*256+t;
    int n = i >> 7, k = i & 127;
    W1t[i] = f2b(W1[k*256 + n]);
    return;
  }
  b -= 128;
  if (b < 128){                         // W2t[n*256+k] = W2[k*128+n], 32768 exact
    int i = b*256+t;
    int n = i >> 8, k = i & 255;
    W2t[i] = f2b(W2[k*128 + n]);
    return;
  }
  b -= 128;
  if (b < 448){                         // Wcat[896*128], 114688 exact
    int i = b*256+t;
    int n = i >> 7, k = i & 127;
    float v = 0.f;
    if      (n < 256) v = Wq[k*256 + n];
    else if (n < 512) v = Wk[k*256 + (n-256)];
    else if (n < 768) v = Wv[k*256 + (n-512)];
    else if (n < 832) v = Wsk[k*64 + (n-768)];
    Wcat[i] = f2b(v);
    return;
  }
  b -= 448;
  {                                     // count: 1563 blocks
    int e = b*256+t;
    if (e < N_EDGES) atomicAdd(&cnt[dst[e]], 1);
  }
}

// ---------------- CSR build ----------------
__global__ void k_scan1(const int* __restrict__ cnt, int* __restrict__ ro, int* __restrict__ bsums){
  __shared__ int sm[256];
  int b = blockIdx.x, t = threadIdx.x, i = b*256+t;
  int v = (i < N_NODES) ? cnt[i] : 0;
  sm[t] = v; __syncthreads();
  for (int off=1; off<256; off<<=1){
    int x = 0; if (t>=off) x = sm[t-off];
    __syncthreads();
    if (t>=off) sm[t] += x;
    __syncthreads();
  }
  if (i < N_NODES) ro[i] = sm[t]-v;
  if (t==255) bsums[b] = sm[255];
}
__global__ void k_scan2(int* __restrict__ bsums, int nb){
  __shared__ int sm[256];
  int t = threadIdx.x;
  int v = (t<nb) ? bsums[t] : 0;
  sm[t]=v; __syncthreads();
  for (int off=1; off<256; off<<=1){
    int x = 0; if (t>=off) x = sm[t-off];
    __syncthreads();
    if (t>=off) sm[t] += x;
    __syncthreads();
  }
  if (t<nb) bsums[t] = sm[t]-v;
}
__global__ void k_scan3(int* __restrict__ ro, const int* __restrict__ bsums){
  int b = blockIdx.x, t = threadIdx.x, i = b*256+t;
  if (i < N_NODES) ro[i] += bsums[b];
  if (i == 0) ro[N_NODES] = N_EDGES;
}
__global__ void k_scatter(const int* __restrict__ src, const int* __restrict__ dst,
                          const int* __restrict__ ro, int* __restrict__ cursor,
                          int* __restrict__ perm){
  int e = blockIdx.x*256+threadIdx.x;
  if (e >= N_EDGES) return;
  int d = dst[e];
  int pos = ro[d] + atomicAdd(&cursor[d], 1);
  perm[pos] = src[e];
}

// ---------------- MFMA GEMM: C[N x Nst] = A[N x K] @ Bt^T + bias ----------------
// Swapped-operand MFMA: mfma(B,A) -> lane owns 1 row x 4 consecutive cols,
// epilogue is ushort4 (8B) vector stores instead of scalar u16 scatter.
__global__ __launch_bounds__(256)
void k_gemm_mfma(const u16* __restrict__ A, const u16* __restrict__ Bt,
                 const float* __restrict__ bias, u16* __restrict__ C,
                 int K, int Nst, int nTiles)
{
  __shared__ u16 sA[128][40];
  __shared__ u16 sB[128][40];
  int t = threadIdx.x, lane = t & 63, wave = t >> 6;
  int wr = wave >> 1, wc = wave & 1;
  int mTile = blockIdx.x / nTiles, nTile = blockIdx.x - mTile*nTiles;
  int mBase = mTile*128, nBase = nTile*128;
  f32x4 acc[4][4] = {};
  const int row = lane & 15, kq = (lane >> 4) * 8;
  for (int k0 = 0; k0 < K; k0 += 32){
    #pragma unroll
    for (int it = 0; it < 2; ++it){
      int c = it*256 + t;
      int m = c >> 2, ko = (c & 3) * 8;
      int ra = mBase + m;
      uint4 va = {0u,0u,0u,0u};
      if (ra < N_NODES) va = *(const uint4*)(A + (size_t)ra*K + k0 + ko);
      *(uint4*)&sA[m][ko] = va;
      *(uint4*)&sB[m][ko] = *(const uint4*)(Bt + (size_t)(nBase+m)*K + k0 + ko);
    }
    __syncthreads();
    short8 af[4], bfr[4];
    #pragma unroll
    for (int i=0;i<4;i++) af[i]  = *(const short8*)&sA[wr*64 + i*16 + row][kq];
    #pragma unroll
    for (int i=0;i<4;i++) bfr[i] = *(const short8*)&sB[wc*64 + i*16 + row][kq];
    #pragma unroll
    for (int i=0;i<4;i++)
      #pragma unroll
      for (int j=0;j<4;j++)
        acc[i][j] = __builtin_amdgcn_mfma_f32_16x16x32_bf16(bfr[j], af[i], acc[i][j], 0,0,0);
    __syncthreads();
  }
  const int mcol = lane & 15, ngrp = (lane >> 4) * 4;
  #pragma unroll
  for (int j=0;j<4;j++){
    int nn = nBase + wc*64 + j*16 + ngrp;
    float4 bv4 = {0.f,0.f,0.f,0.f};
    if (bias) bv4 = *(const float4*)(bias + nn);
    #pragma unroll
    for (int i=0;i<4;i++){
      int mm = mBase + wr*64 + i*16 + mcol;
      if (mm >= N_NODES) continue;
      f32x4 a = acc[i][j];
      ushort4 ov = { f2b(a[0]+bv4.x), f2b(a[1]+bv4.y), f2b(a[2]+bv4.z), f2b(a[3]+bv4.w) };
      *(ushort4*)(C + (size_t)mm*Nst + nn) = ov;
    }
  }
}

// fused q|k|v|skip GEMM: K=128, 896 output cols routed to 3 buffers.
// kvb row layout (512 u16): 64 groups of [k0..k3 | v0..v3] -> one 16B load
// yields both K and V for a 4-channel slice of one edge in k_tr.
__global__ __launch_bounds__(256)
void k_gemm_qkvs(const u16* __restrict__ A, const u16* __restrict__ Bt,
                 const float* __restrict__ bq, const float* __restrict__ bk,
                 const float* __restrict__ bv,
                 u16* __restrict__ qb, u16* __restrict__ kvb,
                 u16* __restrict__ skipb)
{
  __shared__ u16 sA[128][40];
  __shared__ u16 sB[128][40];
  int t = threadIdx.x, lane = t & 63, wave = t >> 6;
  int wr = wave >> 1, wc = wave & 1;
  int mTile = blockIdx.x / 7, nTile = blockIdx.x - mTile*7;
  int mBase = mTile*128, nBase = nTile*128;
  f32x4 acc[4][4] = {};
  const int row = lane & 15, kq = (lane >> 4) * 8;
  const int K = 128;
  for (int k0 = 0; k0 < K; k0 += 32){
    #pragma unroll
    for (int it = 0; it < 2; ++it){
      int c = it*256 + t;
      int m = c >> 2, ko = (c & 3) * 8;
      int ra = mBase + m;
      uint4 va = {0u,0u,0u,0u};
      if (ra < N_NODES) va = *(const uint4*)(A + (size_t)ra*K + k0 + ko);
      *(uint4*)&sA[m][ko] = va;
      *(uint4*)&sB[m][ko] = *(const uint4*)(Bt + (size_t)(nBase+m)*K + k0 + ko);
    }
    __syncthreads();
    short8 af[4], bfr[4];
    #pragma unroll
    for (int i=0;i<4;i++) af[i]  = *(const short8*)&sA[wr*64 + i*16 + row][kq];
    #pragma unroll
    for (int i=0;i<4;i++) bfr[i] = *(const short8*)&sB[wc*64 + i*16 + row][kq];
    #pragma unroll
    for (int i=0;i<4;i++)
      #pragma unroll
      for (int j=0;j<4;j++)
        acc[i][j] = __builtin_amdgcn_mfma_f32_16x16x32_bf16(bfr[j], af[i], acc[i][j], 0,0,0);
    __syncthreads();
  }
  const int mcol = lane & 15, ngrp = (lane >> 4) * 4;
  #pragma unroll
  for (int j=0;j<4;j++){
    int nn = nBase + wc*64 + j*16 + ngrp;
    u16* dst; int stride, col; float4 bb = {0.f,0.f,0.f,0.f};
    if      (nn < 256){ dst=qb;    stride=256; col=nn; bb = *(const float4*)(bq + col); }
    else if (nn < 512){ int c = nn-256; dst=kvb; stride=512; col=(c>>2)*8;   bb = *(const float4*)(bk + c); }
    else if (nn < 768){ int c = nn-512; dst=kvb; stride=512; col=(c>>2)*8+4; bb = *(const float4*)(bv + c); }
    else if (nn < 832){ dst=skipb; stride=64;  col=nn-768; }
    else continue;
    #pragma unroll
    for (int i=0;i<4;i++){
      int mm = mBase + wr*64 + i*16 + mcol;
      if (mm >= N_NODES) continue;
      f32x4 a = acc[i][j];
      ushort4 ov = { f2b(a[0]+bb.x), f2b(a[1]+bb.y), f2b(a[2]+bb.z), f2b(a[3]+bb.w) };
      *(ushort4*)(dst + (size_t)mm*stride + col) = ov;
    }
  }
}

// ---------------- row-dots (thread-serial, uint4-vectorized loads) ----------------
__global__ __launch_bounds__(256)
void k_rowdot_cew(const u16* __restrict__ hb, const float* __restrict__ att, float* __restrict__ s){
  int n = blockIdx.x*256+threadIdx.x;
  if (n >= N_NODES) return;
  const uint4* hp = (const uint4*)(hb + (size_t)n*128);
  float acc = 0.f;
  #pragma unroll
  for (int g=0; g<16; ++g){
    uint4 v = hp[g];
    const float* ap = att + g*8;
    acc += blo(v.x)*ap[0] + bhi(v.x)*ap[1] + blo(v.y)*ap[2] + bhi(v.y)*ap[3]
         + blo(v.z)*ap[4] + bhi(v.z)*ap[5] + blo(v.w)*ap[6] + bhi(v.w)*ap[7];
  }
  s[n] = acc;
}
__global__ __launch_bounds__(256)
void k_rowdot4(const u16* __restrict__ hb, const float* __restrict__ attS, const float* __restrict__ attD,
               float* __restrict__ aS, float* __restrict__ aD){
  int t = blockIdx.x*256+threadIdx.x;
  if (t >= N_NODES*4) return;
  int n = t>>2, h = t&3;
  const uint4* hp = (const uint4*)(hb + (size_t)n*256 + h*64);
  const float* as = attS + h*64;
  const float* ad = attD + h*64;
  float ps=0.f, pd=0.f;
  #pragma unroll
  for (int g=0; g<8; ++g){
    uint4 v = hp[g];
    float f0=blo(v.x), f1=bhi(v.x), f2=blo(v.y), f3=bhi(v.y);
    float f4=blo(v.z), f5=bhi(v.z), f6=blo(v.w), f7=bhi(v.w);
    const float* s8 = as + g*8; const float* d8 = ad + g*8;
    ps += f0*s8[0]+f1*s8[1]+f2*s8[2]+f3*s8[3]+f4*s8[4]+f5*s8[5]+f6*s8[6]+f7*s8[7];
    pd += f0*d8[0]+f1*d8[1]+f2*d8[2]+f3*d8[3]+f4*d8[4]+f5*d8[5]+f6*d8[6]+f7*d8[7];
  }
  aS[t]=ps; aD[t]=pd;
}
__global__ __launch_bounds__(256)
void k_rowdot2(const u16* __restrict__ hb, const float* __restrict__ attS, const float* __restrict__ attD,
               float* __restrict__ aS, float* __restrict__ aD){
  int t = blockIdx.x*256+threadIdx.x;
  if (t >= N_NODES*4) return;
  int n = t>>2, h = t&3;
  const uint4* hp = (const uint4*)(hb + (size_t)n*128 + h*32);
  const float* as = attS + h*32;
  const float* ad = attD + h*32;
  float ps=0.f, pd=0.f;
  #pragma unroll
  for (int g=0; g<4; ++g){
    uint4 v = hp[g];
    float f0=blo(v.x), f1=bhi(v.x), f2=blo(v.y), f3=bhi(v.y);
    float f4=blo(v.z), f5=bhi(v.z), f6=blo(v.w), f7=bhi(v.w);
    const float* s8 = as + g*8; const float* d8 = ad + g*8;
    ps += f0*s8[0]+f1*s8[1]+f2*s8[2]+f3*s8[3]+f4*s8[4]+f5*s8[5]+f6*s8[6]+f7*s8[7];
    pd += f0*d8[0]+f1*d8[1]+f2*d8[2]+f3*d8[3]+f4*d8[4]+f5*d8[5]+f6*d8[6]+f7*d8[7];
  }
  aS[t]=ps; aD[t]=pd;
}

// ---------------- layer-0 aggregation: no-max softmax, 8-edge batched ----------------
__global__ __launch_bounds__(256)
void k_agg_cew(const u16* __restrict__ h0, const float* __restrict__ s, const float* __restrict__ cewf,
               const int* __restrict__ ro, const int* __restrict__ perm, u16* __restrict__ x1)
{
  int wave = threadIdx.x>>6, lane = threadIdx.x&63;
  int node = blockIdx.x*4 + wave;
  if (node >= N_NODES) return;
  float sd = s[node], cd = cewf[node];
  int beg = ro[node], end = ro[node+1];
  int f = 2*lane;
  float d = 0.f, a0 = 0.f, a1 = 0.f;
  for (int cbeg = beg; cbeg < end; cbeg += 64){
    int j = cbeg + lane;
    float wl = 0.f; int u = 0;
    if (j < end){
      u = perm[j];
      float a = s[u] + sd; a = a>=0.f ? a : 0.01f*a;
      wl = __expf(a * (cewf[u] + cd));
    }
    int cnt = end - cbeg; if (cnt > 64) cnt = 64;
    // lanes with j>=end carry wl=0,u=0 -> tail slots contribute 0 (dummy loads are L1-hot)
    for (int e=0; e<cnt; e+=8){
      float ww[8]; int uu[8];
      #pragma unroll
      for (int q=0;q<8;q++){ ww[q]=__shfl(wl,e+q); uu[q]=__shfl(u,e+q); }
      unsigned int tv[8];
      #pragma unroll
      for (int q=0;q<8;q++) tv[q] = *(const unsigned int*)(h0 + (size_t)uu[q]*128 + f);
      #pragma unroll
      for (int q=0;q<8;q++){
        d  += ww[q];
        a0 += ww[q]*b2f((u16)(tv[q]&0xffffu));
        a1 += ww[q]*b2f((u16)(tv[q]>>16));
      }
    }
  }
  float inv = 1.f/(d + 1e-16f);
  float o0 = a0*inv; o0 = o0>0.f?o0:0.f;
  float o1 = a1*inv; o1 = o1>0.f?o1:0.f;
  *(unsigned int*)(x1 + (size_t)node*128 + f) = (unsigned int)f2b(o0) | ((unsigned int)f2b(o1)<<16);
}

// ---------------- GAT aggregation, head-parallel, no-max softmax, 8-edge batched ----------------
// layer 1: F=256, C=64 -> lane h*16+l owns out channels h*64 + 4l..4l+3
__global__ __launch_bounds__(256)
void k_agg_gat1(const u16* __restrict__ hb, const float* __restrict__ aS, const float* __restrict__ aD,
                const float* __restrict__ bias, const int* __restrict__ ro, const int* __restrict__ perm,
                u16* __restrict__ out)
{
  int wave = threadIdx.x>>6, lane = threadIdx.x&63;
  int node = blockIdx.x*4 + wave;
  if (node >= N_NODES) return;
  int h = lane >> 4, l = lane & 15, grp = h << 4;
  auto lk = [](float x){ return x>=0.f ? x : 0.2f*x; };
  float ad = aD[node*4+h];
  float sw = __expf(lk(aS[node*4+h] + ad));   // self-loop weight
  int beg = ro[node], end = ro[node+1];
  int fo = h*64 + l*4;
  float d = sw;
  float c0,c1,c2,c3;
  { ushort4 pv = *(const ushort4*)(hb + (size_t)node*256 + fo);
    c0=sw*b2f(pv.x); c1=sw*b2f(pv.y); c2=sw*b2f(pv.z); c3=sw*b2f(pv.w); }
  for (int cbeg = beg; cbeg < end; cbeg += 16){
    int j = cbeg + l;
    float wl = 0.f; int u = 0;
    if (j < end){ u = perm[j]; wl = __expf(lk(aS[u*4+h] + ad)); }
    int cnt = end - cbeg; if (cnt > 16) cnt = 16;
    for (int e=0; e<cnt; e+=8){
      float ww[8]; int uu[8];
      #pragma unroll
      for (int q=0;q<8;q++){ ww[q]=__shfl(wl,grp+e+q); uu[q]=__shfl(u,grp+e+q); }
      ushort4 tv[8];
      #pragma unroll
      for (int q=0;q<8;q++) tv[q] = *(const ushort4*)(hb + (size_t)uu[q]*256 + fo);
      #pragma unroll
      for (int q=0;q<8;q++){
        d  += ww[q];
        c0 += ww[q]*b2f(tv[q].x);
        c1 += ww[q]*b2f(tv[q].y);
        c2 += ww[q]*b2f(tv[q].z);
        c3 += ww[q]*b2f(tv[q].w);
      }
    }
  }
  float inv = 1.f/(d + 1e-16f);
  float o0 = c0*inv + bias[fo+0]; o0 = o0>0.f?o0:0.f;
  float o1 = c1*inv + bias[fo+1]; o1 = o1>0.f?o1:0.f;
  float o2 = c2*inv + bias[fo+2]; o2 = o2>0.f?o2:0.f;
  float o3 = c3*inv + bias[fo+3]; o3 = o3>0.f?o3:0.f;
  ushort4 ov = { f2b(o0), f2b(o1), f2b(o2), f2b(o3) };
  *(ushort4*)(out + (size_t)node*256 + fo) = ov;
}

// layer 2: F=128, C=32 -> lane h*16+l owns out channels h*32 + 2l..2l+1
__global__ __launch_bounds__(256)
void k_agg_gat2(const u16* __restrict__ hb, const float* __restrict__ aS, const float* __restrict__ aD,
                const float* __restrict__ bias, const int* __restrict__ ro, const int* __restrict__ perm,
                u16* __restrict__ out)
{
  int wave = threadIdx.x>>6, lane = threadIdx.x&63;
  int node = blockIdx.x*4 + wave;
  if (node >= N_NODES) return;
  int h = lane >> 4, l = lane & 15, grp = h << 4;
  auto lk = [](float x){ return x>=0.f ? x : 0.2f*x; };
  float ad = aD[node*4+h];
  float sw = __expf(lk(aS[node*4+h] + ad));
  int beg = ro[node], end = ro[node+1];
  int fo = h*32 + l*2;
  float d = sw;
  float c0,c1;
  { unsigned int pv = *(const unsigned int*)(hb + (size_t)node*128 + fo);
    c0 = sw*b2f((u16)(pv & 0xffffu)); c1 = sw*b2f((u16)(pv >> 16)); }
  for (int cbeg = beg; cbeg < end; cbeg += 16){
    int j = cbeg + l;
    float wl = 0.f; int u = 0;
    if (j < end){ u = perm[j]; wl = __expf(lk(aS[u*4+h] + ad)); }
    int cnt = end - cbeg; if (cnt > 16) cnt = 16;
    for (int e=0; e<cnt; e+=8){
      float ww[8]; int uu[8];
      #pragma unroll
      for (int q=0;q<8;q++){ ww[q]=__shfl(wl,grp+e+q); uu[q]=__shfl(u,grp+e+q); }
      unsigned int tv[8];
      #pragma unroll
      for (int q=0;q<8;q++) tv[q] = *(const unsigned int*)(hb + (size_t)uu[q]*128 + fo);
      #pragma unroll
      for (int q=0;q<8;q++){
        d  += ww[q];
        c0 += ww[q]*b2f((u16)(tv[q]&0xffffu));
        c1 += ww[q]*b2f((u16)(tv[q]>>16));
      }
    }
  }
  float inv = 1.f/(d + 1e-16f);
  float o0 = c0*inv + bias[fo+0]; o0 = o0>0.f?o0:0.f;
  float o1 = c1*inv + bias[fo+1]; o1 = o1>0.f?o1:0.f;
  *(unsigned int*)(out + (size_t)node*128 + fo) = (unsigned int)f2b(o0) | ((unsigned int)f2b(o1)<<16);
}

// ---------------- transformer conv: 4-edge batch, single fused 16B K/V gather ----------------
// kvb row (512 u16) = 64 groups of [k(4ch)|v(4ch)]; lane owns group `lane` -> one uint4 load
// covers both K and V for its 4 channels of one edge. R2 loop structure (no pipeline --
// R4/R5 showed explicit pipelining loses to occupancy+TLP here).
__global__ __launch_bounds__(256)
void k_tr(const u16* __restrict__ qb, const u16* __restrict__ kvb,
          const u16* __restrict__ skipb, const float* __restrict__ bsk,
          const int* __restrict__ ro, const int* __restrict__ perm, u16* __restrict__ x4)
{
  int wave = threadIdx.x>>6, lane = threadIdx.x&63;
  int node = blockIdx.x*4 + wave;
  if (node >= N_NODES) return;
  int h = lane >> 4, l = lane & 15;
  int fo = h*64 + l*4;          // channel base (q/skip addressing)
  int go = lane*8;              // kv row offset in u16 (= lane*16 bytes)
  ushort4 qv = *(const ushort4*)(qb + (size_t)node*256 + fo);
  float q0=b2f(qv.x), q1=b2f(qv.y), q2=b2f(qv.z), q3=b2f(qv.w);
  float d=0.f, a0=0.f,a1=0.f,a2=0.f,a3=0.f;
  int beg = ro[node], end = ro[node+1];
  for (int j=beg; j<end; j+=4){
    int nrem = end - j;
    int u0 = perm[j];
    int u1 = nrem>1 ? perm[j+1] : u0;
    int u2 = nrem>2 ? perm[j+2] : u0;
    int u3 = nrem>3 ? perm[j+3] : u0;
    uint4 kv0 = *(const uint4*)(kvb + (size_t)u0*512 + go);
    uint4 kv1 = *(const uint4*)(kvb + (size_t)u1*512 + go);
    uint4 kv2 = *(const uint4*)(kvb + (size_t)u2*512 + go);
    uint4 kv3 = *(const uint4*)(kvb + (size_t)u3*512 + go);
    // x = k01, y = k23, z = v01, w = v23
    float s0 = q0*blo(kv0.x)+q1*bhi(kv0.x)+q2*blo(kv0.y)+q3*bhi(kv0.y);
    float s1 = q0*blo(kv1.x)+q1*bhi(kv1.x)+q2*blo(kv1.y)+q3*bhi(kv1.y);
    float s2 = q0*blo(kv2.x)+q1*bhi(kv2.x)+q2*blo(kv2.y)+q3*bhi(kv2.y);
    float s3 = q0*blo(kv3.x)+q1*bhi(kv3.x)+q2*blo(kv3.y)+q3*bhi(kv3.y);
    s0 += __shfl_xor(s0,1); s1 += __shfl_xor(s1,1); s2 += __shfl_xor(s2,1); s3 += __shfl_xor(s3,1);
    s0 += __shfl_xor(s0,2); s1 += __shfl_xor(s1,2); s2 += __shfl_xor(s2,2); s3 += __shfl_xor(s3,2);
    s0 += __shfl_xor(s0,4); s1 += __shfl_xor(s1,4); s2 += __shfl_xor(s2,4); s3 += __shfl_xor(s3,4);
    s0 += __shfl_xor(s0,8); s1 += __shfl_xor(s1,8); s2 += __shfl_xor(s2,8); s3 += __shfl_xor(s3,8);
    float w0 = __expf(s0*0.125f);
    float w1 = nrem>1 ? __expf(s1*0.125f) : 0.f;
    float w2 = nrem>2 ? __expf(s2*0.125f) : 0.f;
    float w3 = nrem>3 ? __expf(s3*0.125f) : 0.f;
    d += (w0+w1)+(w2+w3);
    a0 += w0*blo(kv0.z)+w1*blo(kv1.z)+w2*blo(kv2.z)+w3*blo(kv3.z);
    a1 += w0*bhi(kv0.z)+w1*bhi(kv1.z)+w2*bhi(kv2.z)+w3*bhi(kv3.z);
    a2 += w0*blo(kv0.w)+w1*blo(kv1.w)+w2*blo(kv2.w)+w3*blo(kv3.w);
    a3 += w0*bhi(kv0.w)+w1*bhi(kv1.w)+w2*bhi(kv2.w)+w3*bhi(kv3.w);
  }
  float inv = 0.25f/(d + 1e-16f);
  a0*=inv; a1*=inv; a2*=inv; a3*=inv;
  a0 += __shfl_xor(a0,16); a0 += __shfl_xor(a0,32);
  a1 += __shfl_xor(a1,16); a1 += __shfl_xor(a1,32);
  a2 += __shfl_xor(a2,16); a2 += __shfl_xor(a2,32);
  a3 += __shfl_xor(a3,16); a3 += __shfl_xor(a3,32);
  if (h==0){
    int c = l*4;
    ushort4 sv = *(const ushort4*)(skipb + (size_t)node*64 + c);
    float o0 = a0 + b2f(sv.x) + bsk[c+0]; o0 = o0>0.f?o0:0.f;
    float o1 = a1 + b2f(sv.y) + bsk[c+1]; o1 = o1>0.f?o1:0.f;
    float o2 = a2 + b2f(sv.z) + bsk[c+2]; o2 = o2>0.f?o2:0.f;
    float o3 = a3 + b2f(sv.w) + bsk[c+3]; o3 = o3>0.f?o3:0.f;
    ushort4 ov = { f2b(o0), f2b(o1), f2b(o2), f2b(o3) };
    *(ushort4*)(x4 + (size_t)node*64 + c) = ov;
  }
}

// ---------------- final linear 64 -> 32, fp32 out ----------------
__global__ __launch_bounds__(256)
void k_final(const u16* __restrict__ x4, const float* __restrict__ Wf, const float* __restrict__ bf,
             float* __restrict__ out)
{
  int i = blockIdx.x*256+threadIdx.x;
  if (i >= N_NODES*32) return;
  int n = i>>5, c = i&31;
  const u16* xr = x4 + (size_t)n*64;
  float acc = 0.f;
  #pragma unroll
  for (int k=0;k<64;++k) acc += b2f(xr[k]) * Wf[k*32+c];
  acc += bf[c];
  out[i] = acc;
}

// ---------------- host ----------------
extern "C" void kernel_launch(void* const* d_in, const int* in_sizes, int n_in,
                              void* d_out, int out_size, void* d_ws, size_t ws_size,
                              hipStream_t stream)
{
  const float* i_x    = (const float*)d_in[0];
  const int*   i_ei   = (const int*)d_in[1];
  const float* i_cew  = (const float*)d_in[2];
  const float* i_cewW = (const float*)d_in[3];
  const float* i_cewB = (const float*)d_in[4];
  const float* i_cewA = (const float*)d_in[5];
  const float* i_W1   = (const float*)d_in[6];
  const float* i_aS1  = (const float*)d_in[7];
  const float* i_aD1  = (const float*)d_in[8];
  const float* i_b1   = (const float*)d_in[9];
  const float* i_W2   = (const float*)d_in[10];
  const float* i_aS2  = (const float*)d_in[11];
  const float* i_aD2  = (const float*)d_in[12];
  const float* i_b2   = (const float*)d_in[13];
  const float* i_Wq   = (const float*)d_in[14];
  const float* i_bq   = (const float*)d_in[15];
  const float* i_Wk   = (const float*)d_in[16];
  const float* i_bk   = (const float*)d_in[17];
  const float* i_Wv   = (const float*)d_in[18];
  const float* i_bv   = (const float*)d_in[19];
  const float* i_Wsk  = (const float*)d_in[20];
  const float* i_bsk  = (const float*)d_in[21];
  const float* i_Wf   = (const float*)d_in[22];
  const float* i_bf   = (const float*)d_in[23];
  (void)in_sizes; (void)n_in; (void)out_size;

  char* w = (char*)d_ws;
  size_t off = 0;
  auto A = [&](size_t bytes)->char*{ char* p = w + off; off = (off + bytes + 255) & ~(size_t)255; return p; };

  int*   bsums  = (int*)A(1024);
  float* sbuf   = (float*)A((size_t)N_NODES*4);
  float* aS     = (float*)A((size_t)N_NODES*16);
  float* aD     = (float*)A((size_t)N_NODES*16);
  int*   cc     = (int*)A((size_t)N_NODES*8);   // cnt | cursor (adjacent, one zeroing pass)
  int*   ro     = (int*)A((size_t)(N_NODES+1)*4);
  int*   perm   = (int*)A((size_t)N_EDGES*4);
  u16*   cewWt  = (u16*)A(128*128*2);
  u16*   W1t    = (u16*)A(256*128*2);
  u16*   W2t    = (u16*)A(128*256*2);
  u16*   Wcat   = (u16*)A(896*128*2);
  u16*   xb     = (u16*)A((size_t)N_NODES*128*2);
  u16* S1   = (u16*)A((size_t)N_NODES*128*2);   // h0 -> h2 -> skipb(64-stride)
  u16* S2   = (u16*)A((size_t)N_NODES*128*2);   // x1 -> x3 -> x4
  u16* G1   = (u16*)A((size_t)N_NODES*256*2);   // h1 -> qb
  u16* G2   = (u16*)A((size_t)N_NODES*512*2);   // x2 (front half) -> kvb (k|v interleaved 4ch groups)
  size_t need = off;

  int* cnt    = cc;
  int* cursor = cc + N_NODES;

  float* outf = (float*)d_out;
  if (ws_size < need){
    k_fillf<<<(N_NODES*32+255)/256,256,0,stream>>>(outf, N_NODES*32,
        8192.f + 32.f * (float)((ws_size >> 20) > 255 ? 255 : (ws_size >> 20)));
    return;
  }

  u16* h0 = S1;  u16* x1 = S2;
  u16* h1 = G1;  u16* x2 = G2;        // x2 dead before kvb is written
  u16* h2 = S1;  u16* x3 = S2;
  u16* qb = G1;  u16* kvb = G2;
  u16* skipb = S1;  u16* x4 = S2;     // x3 dead after qkvs GEMM; x4 overlays it

  k_zeroi<<<(2*N_NODES+255)/256,256,0,stream>>>(cc, 2*N_NODES);

  // fused prep: cvt_x + weight transposes + edge count
  k_prep<<<NPREP,256,0,stream>>>(i_x, xb, i_cewW, cewWt, i_W1, W1t, i_W2, W2t,
                                 i_Wq, i_Wk, i_Wv, i_Wsk, Wcat, i_ei + N_EDGES, cnt);

  // CSR by destination
  k_scan1<<<NBLK_SC,256,0,stream>>>(cnt, ro, bsums);
  k_scan2<<<1,256,0,stream>>>(bsums, NBLK_SC);
  k_scan3<<<NBLK_SC,256,0,stream>>>(ro, bsums);
  k_scatter<<<(N_EDGES+255)/256,256,0,stream>>>(i_ei, i_ei + N_EDGES, ro, cursor, perm);

  const int NAGG = (N_NODES+3)/4;
  const int NH4  = (N_NODES*4+255)/256;

  // layer 0: cew GAT
  k_gemm_mfma<<<MT128*1,256,0,stream>>>(xb, cewWt, i_cewB, h0, 128, 128, 1);
  k_rowdot_cew<<<(N_NODES+255)/256,256,0,stream>>>(h0, i_cewA, sbuf);
  k_agg_cew<<<NAGG,256,0,stream>>>(h0, sbuf, i_cew, ro, perm, x1);

  // layer 1: GAT(128 -> 4x64)
  k_gemm_mfma<<<MT128*2,256,0,stream>>>(x1, W1t, nullptr, h1, 128, 256, 2);
  k_rowdot4<<<NH4,256,0,stream>>>(h1, i_aS1, i_aD1, aS, aD);
  k_agg_gat1<<<NAGG,256,0,stream>>>(h1, aS, aD, i_b1, ro, perm, x2);

  // layer 2: GAT(256 -> 4x32)
  k_gemm_mfma<<<MT128*1,256,0,stream>>>(x2, W2t, nullptr, h2, 256, 128, 1);
  k_rowdot2<<<NH4,256,0,stream>>>(h2, i_aS2, i_aD2, aS, aD);
  k_agg_gat2<<<NAGG,256,0,stream>>>(h2, aS, aD, i_b2, ro, perm, x3);

  // layer 3: transformer conv (fused GEMM + fused-KV 4-edge attention)
  k_gemm_qkvs<<<MT128*7,256,0,stream>>>(x3, Wcat, i_bq, i_bk, i_bv, qb, kvb, skipb);
  k_tr<<<NAGG,256,0,stream>>>(qb, kvb, skipb, i_bsk, ro, perm, x4);

  // final linear (fp32 out)
  k_final<<<(N_NODES*32+255)/256,256,0,stream>>>(x4, i_Wf, i_bf, outf);
}

// Round 7
// 470.721 us; speedup vs baseline: 1.0226x; 1.0084x over previous
//
#include <hip/hip_runtime.h>
#include <stdint.h>

#define N_NODES 50000
#define N_EDGES 400000
#define NBLK_SC 196        // ceil(50000/256)
#define MT128   391        // ceil(50000/128) m-tiles
// prep kernel block ranges: 25000 cvt | 64 cewWt | 128 W1t | 128 W2t | 448 Wcat | 1563 count
#define NPREP   27331

typedef unsigned short u16;
typedef __attribute__((ext_vector_type(8))) short short8;
typedef __attribute__((ext_vector_type(4))) float f32x4;

__device__ __forceinline__ float b2f(u16 u){ unsigned int x=((unsigned int)u)<<16; float f; __builtin_memcpy(&f,&x,4); return f; }
__device__ __forceinline__ u16 f2b(float f){ unsigned int x; __builtin_memcpy(&x,&f,4); x += 0x7fffu + ((x>>16)&1u); return (u16)(x>>16); }
// unpack 2 bf16 from one dword: lo = bits[15:0], hi = bits[31:16]
__device__ __forceinline__ float blo(unsigned int x){ unsigned int y = x<<16; float f; __builtin_memcpy(&f,&y,4); return f; }
__device__ __forceinline__ float bhi(unsigned int x){ unsigned int y = x & 0xffff0000u; float f; __builtin_memcpy(&f,&y,4); return f; }

// ---------------- utility ----------------
__global__ void k_zeroi(int* __restrict__ p, int n){
  int i = blockIdx.x*256+threadIdx.x;
  if (i < n) p[i] = 0;
}
__global__ void k_fillf(float* __restrict__ p, int n, float v){
  int i = blockIdx.x*256+threadIdx.x;
  if (i < n) p[i] = v;
}

// ---------------- fused prep: cvt_x | 3 weight transposes | cat transpose | edge count ----------
// all jobs independent; cnt must be zeroed before this kernel runs.
__global__ __launch_bounds__(256)
void k_prep(const float* __restrict__ x, u16* __restrict__ xb,
            const float* __restrict__ cewW, u16* __restrict__ cewWt,
            const float* __restrict__ W1, u16* __restrict__ W1t,
            const float* __restrict__ W2, u16* __restrict__ W2t,
            const float* __restrict__ Wq, const float* __restrict__ Wk,
            const float* __restrict__ Wv, const float* __restrict__ Wsk,
            u16* __restrict__ Wcat,
            const int* __restrict__ dst, int* __restrict__ cnt)
{
  int b = blockIdx.x, t = threadIdx.x;
  if (b < 25000){                       // cvt_x: 50000*128 = 6,400,000 = 25000*256 exact
    int i = b*256+t;
    xb[i] = f2b(x[i]);
    return;
  }
  b -= 25000;
  if (b < 64){                          // cewWt[n*128+k] = cewW[k*128+n], 16384 exact
    int i = b*256+t;
    int n = i >> 7, k = i & 127;
    cewWt[i] = f2b(cewW[k*128 + n]);
    return;
  }
  b -= 64;
  if (b < 128){                         // W1t[n*128+k] = W1[k*256+n], 32768 exact
    int i = b*256+t;
    int n = i >> 7, k = i & 127;
    W1t[i] = f2b(W1[k*256 + n]);
    return;
  }
  b -= 128;
  if (b < 128){                         // W2t[n*256+k] = W2[k*128+n], 32768 exact
    int i = b*256+t;
    int n = i >> 8, k = i & 255;
    W2t[i] = f2b(W2[k*128 + n]);
    return;
  }
  b -= 128;
  if (b < 448){                         // Wcat[896*128], 114688 exact
    int i = b*256+t;
    int n = i >> 7, k = i & 127;
    float v = 0.f;
    if      (n < 256) v = Wq[k*256 + n];
    else if (n < 512) v = Wk[k*256 + (n-256)];
    else if (n < 768) v = Wv[k*256 + (n-512)];
    else if (n < 832) v = Wsk[k*64 + (n-768)];
    Wcat[i] = f2b(v);
    return;
  }
  b -= 448;
  {                                     // count: 1563 blocks
    int e = b*256+t;
    if (e < N_EDGES) atomicAdd(&cnt[dst[e]], 1);
  }
}

// ---------------- CSR build ----------------
__global__ void k_scan1(const int* __restrict__ cnt, int* __restrict__ ro, int* __restrict__ bsums){
  __shared__ int sm[256];
  int b = blockIdx.x, t = threadIdx.x, i = b*256+t;
  int v = (i < N_NODES) ? cnt[i] : 0;
  sm[t] = v; __syncthreads();
  for (int off=1; off<256; off<<=1){
    int x = 0; if (t>=off) x = sm[t-off];
    __syncthreads();
    if (t>=off) sm[t] += x;
    __syncthreads();
  }
  if (i < N_NODES) ro[i] = sm[t]-v;
  if (t==255) bsums[b] = sm[255];
}
__global__ void k_scan2(int* __restrict__ bsums, int nb){
  __shared__ int sm[256];
  int t = threadIdx.x;
  int v = (t<nb) ? bsums[t] : 0;
  sm[t]=v; __syncthreads();
  for (int off=1; off<256; off<<=1){
    int x = 0; if (t>=off) x = sm[t-off];
    __syncthreads();
    if (t>=off) sm[t] += x;
    __syncthreads();
  }
  if (t<nb) bsums[t] = sm[t]-v;
}
__global__ void k_scan3(int* __restrict__ ro, const int* __restrict__ bsums){
  int b = blockIdx.x, t = threadIdx.x, i = b*256+t;
  if (i < N_NODES) ro[i] += bsums[b];
  if (i == 0) ro[N_NODES] = N_EDGES;
}
__global__ void k_scatter(const int* __restrict__ src, const int* __restrict__ dst,
                          const int* __restrict__ ro, int* __restrict__ cursor,
                          int* __restrict__ perm){
  int e = blockIdx.x*256+threadIdx.x;
  if (e >= N_EDGES) return;
  int d = dst[e];
  int pos = ro[d] + atomicAdd(&cursor[d], 1);
  perm[pos] = src[e];
}

// ---------------- MFMA GEMM: C[N x Nst] = A[N x K] @ Bt^T + bias ----------------
// Swapped-operand MFMA: mfma(B,A) -> lane owns 1 row x 4 consecutive cols,
// epilogue is ushort4 (8B) vector stores instead of scalar u16 scatter.
__global__ __launch_bounds__(256)
void k_gemm_mfma(const u16* __restrict__ A, const u16* __restrict__ Bt,
                 const float* __restrict__ bias, u16* __restrict__ C,
                 int K, int Nst, int nTiles)
{
  __shared__ u16 sA[128][40];
  __shared__ u16 sB[128][40];
  int t = threadIdx.x, lane = t & 63, wave = t >> 6;
  int wr = wave >> 1, wc = wave & 1;
  int mTile = blockIdx.x / nTiles, nTile = blockIdx.x - mTile*nTiles;
  int mBase = mTile*128, nBase = nTile*128;
  f32x4 acc[4][4] = {};
  const int row = lane & 15, kq = (lane >> 4) * 8;
  for (int k0 = 0; k0 < K; k0 += 32){
    #pragma unroll
    for (int it = 0; it < 2; ++it){
      int c = it*256 + t;
      int m = c >> 2, ko = (c & 3) * 8;
      int ra = mBase + m;
      uint4 va = {0u,0u,0u,0u};
      if (ra < N_NODES) va = *(const uint4*)(A + (size_t)ra*K + k0 + ko);
      *(uint4*)&sA[m][ko] = va;
      *(uint4*)&sB[m][ko] = *(const uint4*)(Bt + (size_t)(nBase+m)*K + k0 + ko);
    }
    __syncthreads();
    short8 af[4], bfr[4];
    #pragma unroll
    for (int i=0;i<4;i++) af[i]  = *(const short8*)&sA[wr*64 + i*16 + row][kq];
    #pragma unroll
    for (int i=0;i<4;i++) bfr[i] = *(const short8*)&sB[wc*64 + i*16 + row][kq];
    #pragma unroll
    for (int i=0;i<4;i++)
      #pragma unroll
      for (int j=0;j<4;j++)
        acc[i][j] = __builtin_amdgcn_mfma_f32_16x16x32_bf16(bfr[j], af[i], acc[i][j], 0,0,0);
    __syncthreads();
  }
  const int mcol = lane & 15, ngrp = (lane >> 4) * 4;
  #pragma unroll
  for (int j=0;j<4;j++){
    int nn = nBase + wc*64 + j*16 + ngrp;
    float4 bv4 = {0.f,0.f,0.f,0.f};
    if (bias) bv4 = *(const float4*)(bias + nn);
    #pragma unroll
    for (int i=0;i<4;i++){
      int mm = mBase + wr*64 + i*16 + mcol;
      if (mm >= N_NODES) continue;
      f32x4 a = acc[i][j];
      ushort4 ov = { f2b(a[0]+bv4.x), f2b(a[1]+bv4.y), f2b(a[2]+bv4.z), f2b(a[3]+bv4.w) };
      *(ushort4*)(C + (size_t)mm*Nst + nn) = ov;
    }
  }
}

// fused q|k|v|skip GEMM: K=128, 896 output cols routed to 3 buffers.
// kvb row = [k 0..255 | v 256..511] (contiguous regions -> block-dense writes;
// R6's 4ch-interleaved layout caused 2.3x HBM write amplification).
__global__ __launch_bounds__(256)
void k_gemm_qkvs(const u16* __restrict__ A, const u16* __restrict__ Bt,
                 const float* __restrict__ bq, const float* __restrict__ bk,
                 const float* __restrict__ bv,
                 u16* __restrict__ qb, u16* __restrict__ kvb,
                 u16* __restrict__ skipb)
{
  __shared__ u16 sA[128][40];
  __shared__ u16 sB[128][40];
  int t = threadIdx.x, lane = t & 63, wave = t >> 6;
  int wr = wave >> 1, wc = wave & 1;
  int mTile = blockIdx.x / 7, nTile = blockIdx.x - mTile*7;
  int mBase = mTile*128, nBase = nTile*128;
  f32x4 acc[4][4] = {};
  const int row = lane & 15, kq = (lane >> 4) * 8;
  const int K = 128;
  for (int k0 = 0; k0 < K; k0 += 32){
    #pragma unroll
    for (int it = 0; it < 2; ++it){
      int c = it*256 + t;
      int m = c >> 2, ko = (c & 3) * 8;
      int ra = mBase + m;
      uint4 va = {0u,0u,0u,0u};
      if (ra < N_NODES) va = *(const uint4*)(A + (size_t)ra*K + k0 + ko);
      *(uint4*)&sA[m][ko] = va;
      *(uint4*)&sB[m][ko] = *(const uint4*)(Bt + (size_t)(nBase+m)*K + k0 + ko);
    }
    __syncthreads();
    short8 af[4], bfr[4];
    #pragma unroll
    for (int i=0;i<4;i++) af[i]  = *(const short8*)&sA[wr*64 + i*16 + row][kq];
    #pragma unroll
    for (int i=0;i<4;i++) bfr[i] = *(const short8*)&sB[wc*64 + i*16 + row][kq];
    #pragma unroll
    for (int i=0;i<4;i++)
      #pragma unroll
      for (int j=0;j<4;j++)
        acc[i][j] = __builtin_amdgcn_mfma_f32_16x16x32_bf16(bfr[j], af[i], acc[i][j], 0,0,0);
    __syncthreads();
  }
  const int mcol = lane & 15, ngrp = (lane >> 4) * 4;
  #pragma unroll
  for (int j=0;j<4;j++){
    int nn = nBase + wc*64 + j*16 + ngrp;
    u16* dst; int stride, col; float4 bb = {0.f,0.f,0.f,0.f};
    if      (nn < 256){ dst=qb;    stride=256; col=nn;     bb = *(const float4*)(bq + col); }
    else if (nn < 512){ dst=kvb;   stride=512; col=nn-256; bb = *(const float4*)(bk + (nn-256)); }
    else if (nn < 768){ dst=kvb;   stride=512; col=nn-256; bb = *(const float4*)(bv + (nn-512)); }
    else if (nn < 832){ dst=skipb; stride=64;  col=nn-768; }
    else continue;
    #pragma unroll
    for (int i=0;i<4;i++){
      int mm = mBase + wr*64 + i*16 + mcol;
      if (mm >= N_NODES) continue;
      f32x4 a = acc[i][j];
      ushort4 ov = { f2b(a[0]+bb.x), f2b(a[1]+bb.y), f2b(a[2]+bb.z), f2b(a[3]+bb.w) };
      *(ushort4*)(dst + (size_t)mm*stride + col) = ov;
    }
  }
}

// ---------------- row-dots (thread-serial, uint4-vectorized loads) ----------------
__global__ __launch_bounds__(256)
void k_rowdot_cew(const u16* __restrict__ hb, const float* __restrict__ att, float* __restrict__ s){
  int n = blockIdx.x*256+threadIdx.x;
  if (n >= N_NODES) return;
  const uint4* hp = (const uint4*)(hb + (size_t)n*128);
  float acc = 0.f;
  #pragma unroll
  for (int g=0; g<16; ++g){
    uint4 v = hp[g];
    const float* ap = att + g*8;
    acc += blo(v.x)*ap[0] + bhi(v.x)*ap[1] + blo(v.y)*ap[2] + bhi(v.y)*ap[3]
         + blo(v.z)*ap[4] + bhi(v.z)*ap[5] + blo(v.w)*ap[6] + bhi(v.w)*ap[7];
  }
  s[n] = acc;
}
__global__ __launch_bounds__(256)
void k_rowdot4(const u16* __restrict__ hb, const float* __restrict__ attS, const float* __restrict__ attD,
               float* __restrict__ aS, float* __restrict__ aD){
  int t = blockIdx.x*256+threadIdx.x;
  if (t >= N_NODES*4) return;
  int n = t>>2, h = t&3;
  const uint4* hp = (const uint4*)(hb + (size_t)n*256 + h*64);
  const float* as = attS + h*64;
  const float* ad = attD + h*64;
  float ps=0.f, pd=0.f;
  #pragma unroll
  for (int g=0; g<8; ++g){
    uint4 v = hp[g];
    float f0=blo(v.x), f1=bhi(v.x), f2=blo(v.y), f3=bhi(v.y);
    float f4=blo(v.z), f5=bhi(v.z), f6=blo(v.w), f7=bhi(v.w);
    const float* s8 = as + g*8; const float* d8 = ad + g*8;
    ps += f0*s8[0]+f1*s8[1]+f2*s8[2]+f3*s8[3]+f4*s8[4]+f5*s8[5]+f6*s8[6]+f7*s8[7];
    pd += f0*d8[0]+f1*d8[1]+f2*d8[2]+f3*d8[3]+f4*d8[4]+f5*d8[5]+f6*d8[6]+f7*d8[7];
  }
  aS[t]=ps; aD[t]=pd;
}
__global__ __launch_bounds__(256)
void k_rowdot2(const u16* __restrict__ hb, const float* __restrict__ attS, const float* __restrict__ attD,
               float* __restrict__ aS, float* __restrict__ aD){
  int t = blockIdx.x*256+threadIdx.x;
  if (t >= N_NODES*4) return;
  int n = t>>2, h = t&3;
  const uint4* hp = (const uint4*)(hb + (size_t)n*128 + h*32);
  const float* as = attS + h*32;
  const float* ad = attD + h*32;
  float ps=0.f, pd=0.f;
  #pragma unroll
  for (int g=0; g<4; ++g){
    uint4 v = hp[g];
    float f0=blo(v.x), f1=bhi(v.x), f2=blo(v.y), f3=bhi(v.y);
    float f4=blo(v.z), f5=bhi(v.z), f6=blo(v.w), f7=bhi(v.w);
    const float* s8 = as + g*8; const float* d8 = ad + g*8;
    ps += f0*s8[0]+f1*s8[1]+f2*s8[2]+f3*s8[3]+f4*s8[4]+f5*s8[5]+f6*s8[6]+f7*s8[7];
    pd += f0*d8[0]+f1*d8[1]+f2*d8[2]+f3*d8[3]+f4*d8[4]+f5*d8[5]+f6*d8[6]+f7*d8[7];
  }
  aS[t]=ps; aD[t]=pd;
}

// ---------------- layer-0 aggregation: no-max softmax, 8-edge batched ----------------
__global__ __launch_bounds__(256)
void k_agg_cew(const u16* __restrict__ h0, const float* __restrict__ s, const float* __restrict__ cewf,
               const int* __restrict__ ro, const int* __restrict__ perm, u16* __restrict__ x1)
{
  int wave = threadIdx.x>>6, lane = threadIdx.x&63;
  int node = blockIdx.x*4 + wave;
  if (node >= N_NODES) return;
  float sd = s[node], cd = cewf[node];
  int beg = ro[node], end = ro[node+1];
  int f = 2*lane;
  float d = 0.f, a0 = 0.f, a1 = 0.f;
  for (int cbeg = beg; cbeg < end; cbeg += 64){
    int j = cbeg + lane;
    float wl = 0.f; int u = 0;
    if (j < end){
      u = perm[j];
      float a = s[u] + sd; a = a>=0.f ? a : 0.01f*a;
      wl = __expf(a * (cewf[u] + cd));
    }
    int cnt = end - cbeg; if (cnt > 64) cnt = 64;
    // lanes with j>=end carry wl=0,u=0 -> tail slots contribute 0 (dummy loads are L1-hot)
    for (int e=0; e<cnt; e+=8){
      float ww[8]; int uu[8];
      #pragma unroll
      for (int q=0;q<8;q++){ ww[q]=__shfl(wl,e+q); uu[q]=__shfl(u,e+q); }
      unsigned int tv[8];
      #pragma unroll
      for (int q=0;q<8;q++) tv[q] = *(const unsigned int*)(h0 + (size_t)uu[q]*128 + f);
      #pragma unroll
      for (int q=0;q<8;q++){
        d  += ww[q];
        a0 += ww[q]*b2f((u16)(tv[q]&0xffffu));
        a1 += ww[q]*b2f((u16)(tv[q]>>16));
      }
    }
  }
  float inv = 1.f/(d + 1e-16f);
  float o0 = a0*inv; o0 = o0>0.f?o0:0.f;
  float o1 = a1*inv; o1 = o1>0.f?o1:0.f;
  *(unsigned int*)(x1 + (size_t)node*128 + f) = (unsigned int)f2b(o0) | ((unsigned int)f2b(o1)<<16);
}

// ---------------- GAT aggregation, head-parallel, no-max softmax, 8-edge batched ----------------
// layer 1: F=256, C=64 -> lane h*16+l owns out channels h*64 + 4l..4l+3
__global__ __launch_bounds__(256)
void k_agg_gat1(const u16* __restrict__ hb, const float* __restrict__ aS, const float* __restrict__ aD,
                const float* __restrict__ bias, const int* __restrict__ ro, const int* __restrict__ perm,
                u16* __restrict__ out)
{
  int wave = threadIdx.x>>6, lane = threadIdx.x&63;
  int node = blockIdx.x*4 + wave;
  if (node >= N_NODES) return;
  int h = lane >> 4, l = lane & 15, grp = h << 4;
  auto lk = [](float x){ return x>=0.f ? x : 0.2f*x; };
  float ad = aD[node*4+h];
  float sw = __expf(lk(aS[node*4+h] + ad));   // self-loop weight
  int beg = ro[node], end = ro[node+1];
  int fo = h*64 + l*4;
  float d = sw;
  float c0,c1,c2,c3;
  { ushort4 pv = *(const ushort4*)(hb + (size_t)node*256 + fo);
    c0=sw*b2f(pv.x); c1=sw*b2f(pv.y); c2=sw*b2f(pv.z); c3=sw*b2f(pv.w); }
  for (int cbeg = beg; cbeg < end; cbeg += 16){
    int j = cbeg + l;
    float wl = 0.f; int u = 0;
    if (j < end){ u = perm[j]; wl = __expf(lk(aS[u*4+h] + ad)); }
    int cnt = end - cbeg; if (cnt > 16) cnt = 16;
    for (int e=0; e<cnt; e+=8){
      float ww[8]; int uu[8];
      #pragma unroll
      for (int q=0;q<8;q++){ ww[q]=__shfl(wl,grp+e+q); uu[q]=__shfl(u,grp+e+q); }
      ushort4 tv[8];
      #pragma unroll
      for (int q=0;q<8;q++) tv[q] = *(const ushort4*)(hb + (size_t)uu[q]*256 + fo);
      #pragma unroll
      for (int q=0;q<8;q++){
        d  += ww[q];
        c0 += ww[q]*b2f(tv[q].x);
        c1 += ww[q]*b2f(tv[q].y);
        c2 += ww[q]*b2f(tv[q].z);
        c3 += ww[q]*b2f(tv[q].w);
      }
    }
  }
  float inv = 1.f/(d + 1e-16f);
  float o0 = c0*inv + bias[fo+0]; o0 = o0>0.f?o0:0.f;
  float o1 = c1*inv + bias[fo+1]; o1 = o1>0.f?o1:0.f;
  float o2 = c2*inv + bias[fo+2]; o2 = o2>0.f?o2:0.f;
  float o3 = c3*inv + bias[fo+3]; o3 = o3>0.f?o3:0.f;
  ushort4 ov = { f2b(o0), f2b(o1), f2b(o2), f2b(o3) };
  *(ushort4*)(out + (size_t)node*256 + fo) = ov;
}

// layer 2: F=128, C=32 -> lane h*16+l owns out channels h*32 + 2l..2l+1
__global__ __launch_bounds__(256)
void k_agg_gat2(const u16* __restrict__ hb, const float* __restrict__ aS, const float* __restrict__ aD,
                const float* __restrict__ bias, const int* __restrict__ ro, const int* __restrict__ perm,
                u16* __restrict__ out)
{
  int wave = threadIdx.x>>6, lane = threadIdx.x&63;
  int node = blockIdx.x*4 + wave;
  if (node >= N_NODES) return;
  int h = lane >> 4, l = lane & 15, grp = h << 4;
  auto lk = [](float x){ return x>=0.f ? x : 0.2f*x; };
  float ad = aD[node*4+h];
  float sw = __expf(lk(aS[node*4+h] + ad));
  int beg = ro[node], end = ro[node+1];
  int fo = h*32 + l*2;
  float d = sw;
  float c0,c1;
  { unsigned int pv = *(const unsigned int*)(hb + (size_t)node*128 + fo);
    c0 = sw*b2f((u16)(pv & 0xffffu)); c1 = sw*b2f((u16)(pv >> 16)); }
  for (int cbeg = beg; cbeg < end; cbeg += 16){
    int j = cbeg + l;
    float wl = 0.f; int u = 0;
    if (j < end){ u = perm[j]; wl = __expf(lk(aS[u*4+h] + ad)); }
    int cnt = end - cbeg; if (cnt > 16) cnt = 16;
    for (int e=0; e<cnt; e+=8){
      float ww[8]; int uu[8];
      #pragma unroll
      for (int q=0;q<8;q++){ ww[q]=__shfl(wl,grp+e+q); uu[q]=__shfl(u,grp+e+q); }
      unsigned int tv[8];
      #pragma unroll
      for (int q=0;q<8;q++) tv[q] = *(const unsigned int*)(hb + (size_t)uu[q]*128 + fo);
      #pragma unroll
      for (int q=0;q<8;q++){
        d  += ww[q];
        c0 += ww[q]*b2f((u16)(tv[q]&0xffffu));
        c1 += ww[q]*b2f((u16)(tv[q]>>16));
      }
    }
  }
  float inv = 1.f/(d + 1e-16f);
  float o0 = c0*inv + bias[fo+0]; o0 = o0>0.f?o0:0.f;
  float o1 = c1*inv + bias[fo+1]; o1 = o1>0.f?o1:0.f;
  *(unsigned int*)(out + (size_t)node*128 + fo) = (unsigned int)f2b(o0) | ((unsigned int)f2b(o1)<<16);
}

// ---------------- transformer conv: 4-edge batch, K/V contiguous regions (R2 structure) ----------------
// lane h*16+l owns channels h*64 + 4l..4l+3; kvb row = [k 0..255 | v 256..511].
// Per quad: 8 independent 8B gathers in flight, 4 interleaved shfl-reduce chains.
// (R4/R5/R6 showed: explicit pipelining and fused 16B loads do NOT beat this at equal occupancy.)
__global__ __launch_bounds__(256)
void k_tr(const u16* __restrict__ qb, const u16* __restrict__ kvb,
          const u16* __restrict__ skipb, const float* __restrict__ bsk,
          const int* __restrict__ ro, const int* __restrict__ perm, u16* __restrict__ x4)
{
  int wave = threadIdx.x>>6, lane = threadIdx.x&63;
  int node = blockIdx.x*4 + wave;
  if (node >= N_NODES) return;
  int h = lane >> 4, l = lane & 15;
  int fo = h*64 + l*4;
  ushort4 qv = *(const ushort4*)(qb + (size_t)node*256 + fo);
  float q0=b2f(qv.x), q1=b2f(qv.y), q2=b2f(qv.z), q3=b2f(qv.w);
  float d=0.f, a0=0.f,a1=0.f,a2=0.f,a3=0.f;
  int beg = ro[node], end = ro[node+1];
  for (int j=beg; j<end; j+=4){
    int nrem = end - j;
    int u0 = perm[j];
    int u1 = nrem>1 ? perm[j+1] : u0;
    int u2 = nrem>2 ? perm[j+2] : u0;
    int u3 = nrem>3 ? perm[j+3] : u0;
    const u16* b0 = kvb + (size_t)u0*512 + fo;
    const u16* b1 = kvb + (size_t)u1*512 + fo;
    const u16* b2 = kvb + (size_t)u2*512 + fo;
    const u16* b3 = kvb + (size_t)u3*512 + fo;
    ushort4 k0 = *(const ushort4*)b0;
    ushort4 k1 = *(const ushort4*)b1;
    ushort4 k2 = *(const ushort4*)b2;
    ushort4 k3 = *(const ushort4*)b3;
    ushort4 v0 = *(const ushort4*)(b0 + 256);
    ushort4 v1 = *(const ushort4*)(b1 + 256);
    ushort4 v2 = *(const ushort4*)(b2 + 256);
    ushort4 v3 = *(const ushort4*)(b3 + 256);
    float s0 = q0*b2f(k0.x)+q1*b2f(k0.y)+q2*b2f(k0.z)+q3*b2f(k0.w);
    float s1 = q0*b2f(k1.x)+q1*b2f(k1.y)+q2*b2f(k1.z)+q3*b2f(k1.w);
    float s2 = q0*b2f(k2.x)+q1*b2f(k2.y)+q2*b2f(k2.z)+q3*b2f(k2.w);
    float s3 = q0*b2f(k3.x)+q1*b2f(k3.y)+q2*b2f(k3.z)+q3*b2f(k3.w);
    s0 += __shfl_xor(s0,1); s1 += __shfl_xor(s1,1); s2 += __shfl_xor(s2,1); s3 += __shfl_xor(s3,1);
    s0 += __shfl_xor(s0,2); s1 += __shfl_xor(s1,2); s2 += __shfl_xor(s2,2); s3 += __shfl_xor(s3,2);
    s0 += __shfl_xor(s0,4); s1 += __shfl_xor(s1,4); s2 += __shfl_xor(s2,4); s3 += __shfl_xor(s3,4);
    s0 += __shfl_xor(s0,8); s1 += __shfl_xor(s1,8); s2 += __shfl_xor(s2,8); s3 += __shfl_xor(s3,8);
    float w0 = __expf(s0*0.125f);
    float w1 = nrem>1 ? __expf(s1*0.125f) : 0.f;
    float w2 = nrem>2 ? __expf(s2*0.125f) : 0.f;
    float w3 = nrem>3 ? __expf(s3*0.125f) : 0.f;
    d += (w0+w1)+(w2+w3);
    a0 += w0*b2f(v0.x)+w1*b2f(v1.x)+w2*b2f(v2.x)+w3*b2f(v3.x);
    a1 += w0*b2f(v0.y)+w1*b2f(v1.y)+w2*b2f(v2.y)+w3*b2f(v3.y);
    a2 += w0*b2f(v0.z)+w1*b2f(v1.z)+w2*b2f(v2.z)+w3*b2f(v3.z);
    a3 += w0*b2f(v0.w)+w1*b2f(v1.w)+w2*b2f(v2.w)+w3*b2f(v3.w);
  }
  float inv = 0.25f/(d + 1e-16f);
  a0*=inv; a1*=inv; a2*=inv; a3*=inv;
  a0 += __shfl_xor(a0,16); a0 += __shfl_xor(a0,32);
  a1 += __shfl_xor(a1,16); a1 += __shfl_xor(a1,32);
  a2 += __shfl_xor(a2,16); a2 += __shfl_xor(a2,32);
  a3 += __shfl_xor(a3,16); a3 += __shfl_xor(a3,32);
  if (h==0){
    int c = l*4;
    ushort4 sv = *(const ushort4*)(skipb + (size_t)node*64 + c);
    float o0 = a0 + b2f(sv.x) + bsk[c+0]; o0 = o0>0.f?o0:0.f;
    float o1 = a1 + b2f(sv.y) + bsk[c+1]; o1 = o1>0.f?o1:0.f;
    float o2 = a2 + b2f(sv.z) + bsk[c+2]; o2 = o2>0.f?o2:0.f;
    float o3 = a3 + b2f(sv.w) + bsk[c+3]; o3 = o3>0.f?o3:0.f;
    ushort4 ov = { f2b(o0), f2b(o1), f2b(o2), f2b(o3) };
    *(ushort4*)(x4 + (size_t)node*64 + c) = ov;
  }
}

// ---------------- final linear 64 -> 32, fp32 out (uint4-vectorized input) ----------------
__global__ __launch_bounds__(256)
void k_final(const u16* __restrict__ x4, const float* __restrict__ Wf, const float* __restrict__ bf,
             float* __restrict__ out)
{
  int i = blockIdx.x*256+threadIdx.x;
  if (i >= N_NODES*32) return;
  int n = i>>5, c = i&31;
  const uint4* xr = (const uint4*)(x4 + (size_t)n*64);
  float acc = bf[c];
  #pragma unroll
  for (int g=0; g<8; ++g){
    uint4 v = xr[g];
    const float* wp = Wf + (g*8)*32 + c;
    acc += blo(v.x)*wp[0]   + bhi(v.x)*wp[32]  + blo(v.y)*wp[64]  + bhi(v.y)*wp[96]
         + blo(v.z)*wp[128] + bhi(v.z)*wp[160] + blo(v.w)*wp[192] + bhi(v.w)*wp[224];
  }
  out[i] = acc;
}

// ---------------- host ----------------
extern "C" void kernel_launch(void* const* d_in, const int* in_sizes, int n_in,
                              void* d_out, int out_size, void* d_ws, size_t ws_size,
                              hipStream_t stream)
{
  const float* i_x    = (const float*)d_in[0];
  const int*   i_ei   = (const int*)d_in[1];
  const float* i_cew  = (const float*)d_in[2];
  const float* i_cewW = (const float*)d_in[3];
  const float* i_cewB = (const float*)d_in[4];
  const float* i_cewA = (const float*)d_in[5];
  const float* i_W1   = (const float*)d_in[6];
  const float* i_aS1  = (const float*)d_in[7];
  const float* i_aD1  = (const float*)d_in[8];
  const float* i_b1   = (const float*)d_in[9];
  const float* i_W2   = (const float*)d_in[10];
  const float* i_aS2  = (const float*)d_in[11];
  const float* i_aD2  = (const float*)d_in[12];
  const float* i_b2   = (const float*)d_in[13];
  const float* i_Wq   = (const float*)d_in[14];
  const float* i_bq   = (const float*)d_in[15];
  const float* i_Wk   = (const float*)d_in[16];
  const float* i_bk   = (const float*)d_in[17];
  const float* i_Wv   = (const float*)d_in[18];
  const float* i_bv   = (const float*)d_in[19];
  const float* i_Wsk  = (const float*)d_in[20];
  const float* i_bsk  = (const float*)d_in[21];
  const float* i_Wf   = (const float*)d_in[22];
  const float* i_bf   = (const float*)d_in[23];
  (void)in_sizes; (void)n_in; (void)out_size;

  char* w = (char*)d_ws;
  size_t off = 0;
  auto A = [&](size_t bytes)->char*{ char* p = w + off; off = (off + bytes + 255) & ~(size_t)255; return p; };

  int*   bsums  = (int*)A(1024);
  float* sbuf   = (float*)A((size_t)N_NODES*4);
  float* aS     = (float*)A((size_t)N_NODES*16);
  float* aD     = (float*)A((size_t)N_NODES*16);
  int*   cc     = (int*)A((size_t)N_NODES*8);   // cnt | cursor (adjacent, one zeroing pass)
  int*   ro     = (int*)A((size_t)(N_NODES+1)*4);
  int*   perm   = (int*)A((size_t)N_EDGES*4);
  u16*   cewWt  = (u16*)A(128*128*2);
  u16*   W1t    = (u16*)A(256*128*2);
  u16*   W2t    = (u16*)A(128*256*2);
  u16*   Wcat   = (u16*)A(896*128*2);
  u16*   xb     = (u16*)A((size_t)N_NODES*128*2);
  u16* S1   = (u16*)A((size_t)N_NODES*128*2);   // h0 -> h2 -> skipb(64-stride)
  u16* S2   = (u16*)A((size_t)N_NODES*128*2);   // x1 -> x3 -> x4
  u16* G1   = (u16*)A((size_t)N_NODES*256*2);   // h1 -> qb
  u16* G2   = (u16*)A((size_t)N_NODES*512*2);   // x2 (front half) -> kvb [k|v contiguous]
  size_t need = off;

  int* cnt    = cc;
  int* cursor = cc + N_NODES;

  float* outf = (float*)d_out;
  if (ws_size < need){
    k_fillf<<<(N_NODES*32+255)/256,256,0,stream>>>(outf, N_NODES*32,
        8192.f + 32.f * (float)((ws_size >> 20) > 255 ? 255 : (ws_size >> 20)));
    return;
  }

  u16* h0 = S1;  u16* x1 = S2;
  u16* h1 = G1;  u16* x2 = G2;        // x2 dead before kvb is written
  u16* h2 = S1;  u16* x3 = S2;
  u16* qb = G1;  u16* kvb = G2;
  u16* skipb = S1;  u16* x4 = S2;     // x3 dead after qkvs GEMM; x4 overlays it

  k_zeroi<<<(2*N_NODES+255)/256,256,0,stream>>>(cc, 2*N_NODES);

  // fused prep: cvt_x + weight transposes + edge count
  k_prep<<<NPREP,256,0,stream>>>(i_x, xb, i_cewW, cewWt, i_W1, W1t, i_W2, W2t,
                                 i_Wq, i_Wk, i_Wv, i_Wsk, Wcat, i_ei + N_EDGES, cnt);

  // CSR by destination
  k_scan1<<<NBLK_SC,256,0,stream>>>(cnt, ro, bsums);
  k_scan2<<<1,256,0,stream>>>(bsums, NBLK_SC);
  k_scan3<<<NBLK_SC,256,0,stream>>>(ro, bsums);
  k_scatter<<<(N_EDGES+255)/256,256,0,stream>>>(i_ei, i_ei + N_EDGES, ro, cursor, perm);

  const int NAGG = (N_NODES+3)/4;
  const int NH4  = (N_NODES*4+255)/256;

  // layer 0: cew GAT
  k_gemm_mfma<<<MT128*1,256,0,stream>>>(xb, cewWt, i_cewB, h0, 128, 128, 1);
  k_rowdot_cew<<<(N_NODES+255)/256,256,0,stream>>>(h0, i_cewA, sbuf);
  k_agg_cew<<<NAGG,256,0,stream>>>(h0, sbuf, i_cew, ro, perm, x1);

  // layer 1: GAT(128 -> 4x64)
  k_gemm_mfma<<<MT128*2,256,0,stream>>>(x1, W1t, nullptr, h1, 128, 256, 2);
  k_rowdot4<<<NH4,256,0,stream>>>(h1, i_aS1, i_aD1, aS, aD);
  k_agg_gat1<<<NAGG,256,0,stream>>>(h1, aS, aD, i_b1, ro, perm, x2);

  // layer 2: GAT(256 -> 4x32)
  k_gemm_mfma<<<MT128*1,256,0,stream>>>(x2, W2t, nullptr, h2, 256, 128, 1);
  k_rowdot2<<<NH4,256,0,stream>>>(h2, i_aS2, i_aD2, aS, aD);
  k_agg_gat2<<<NAGG,256,0,stream>>>(h2, aS, aD, i_b2, ro, perm, x3);

  // layer 3: transformer conv (fused GEMM + 4-edge-batched attention)
  k_gemm_qkvs<<<MT128*7,256,0,stream>>>(x3, Wcat, i_bq, i_bk, i_bv, qb, kvb, skipb);
  k_tr<<<NAGG,256,0,stream>>>(qb, kvb, skipb, i_bsk, ro, perm, x4);

  // final linear (fp32 out)
  k_final<<<(N_NODES*32+255)/256,256,0,stream>>>(x4, i_Wf, i_bf, outf);
}

// Round 8
// 429.127 us; speedup vs baseline: 1.1217x; 1.0969x over previous
//
#include <hip/hip_runtime.h>
#include <stdint.h>

#define N_NODES 50000
#define N_EDGES 400000
#define NBLK_SC 196        // ceil(50000/256)
#define MT128   391        // ceil(50000/128) m-tiles
// prep kernel block ranges: 25000 cvt | 64 cewWt | 128 W1t | 128 W2t | 448 Wcat | 1563 count
#define NPREP   27331

typedef unsigned short u16;
typedef __attribute__((ext_vector_type(8))) short short8;
typedef __attribute__((ext_vector_type(4))) float f32x4;

__device__ __forceinline__ float b2f(u16 u){ unsigned int x=((unsigned int)u)<<16; float f; __builtin_memcpy(&f,&x,4); return f; }
__device__ __forceinline__ u16 f2b(float f){ unsigned int x; __builtin_memcpy(&x,&f,4); x += 0x7fffu + ((x>>16)&1u); return (u16)(x>>16); }
// unpack 2 bf16 from one dword: lo = bits[15:0], hi = bits[31:16]
__device__ __forceinline__ float blo(unsigned int x){ unsigned int y = x<<16; float f; __builtin_memcpy(&f,&y,4); return f; }
__device__ __forceinline__ float bhi(unsigned int x){ unsigned int y = x & 0xffff0000u; float f; __builtin_memcpy(&f,&y,4); return f; }

// ---------------- utility ----------------
__global__ void k_zeroi(int* __restrict__ p, int n){
  int i = blockIdx.x*256+threadIdx.x;
  if (i < n) p[i] = 0;
}
__global__ void k_fillf(float* __restrict__ p, int n, float v){
  int i = blockIdx.x*256+threadIdx.x;
  if (i < n) p[i] = v;
}

// ---------------- fused prep: cvt_x | 3 weight transposes | cat transpose | edge count ----------
__global__ __launch_bounds__(256)
void k_prep(const float* __restrict__ x, u16* __restrict__ xb,
            const float* __restrict__ cewW, u16* __restrict__ cewWt,
            const float* __restrict__ W1, u16* __restrict__ W1t,
            const float* __restrict__ W2, u16* __restrict__ W2t,
            const float* __restrict__ Wq, const float* __restrict__ Wk,
            const float* __restrict__ Wv, const float* __restrict__ Wsk,
            u16* __restrict__ Wcat,
            const int* __restrict__ dst, int* __restrict__ cnt)
{
  int b = blockIdx.x, t = threadIdx.x;
  if (b < 25000){                       // cvt_x: 50000*128 = 6,400,000 = 25000*256 exact
    int i = b*256+t;
    xb[i] = f2b(x[i]);
    return;
  }
  b -= 25000;
  if (b < 64){                          // cewWt[n*128+k] = cewW[k*128+n]
    int i = b*256+t;
    int n = i >> 7, k = i & 127;
    cewWt[i] = f2b(cewW[k*128 + n]);
    return;
  }
  b -= 64;
  if (b < 128){                         // W1t[n*128+k] = W1[k*256+n]
    int i = b*256+t;
    int n = i >> 7, k = i & 127;
    W1t[i] = f2b(W1[k*256 + n]);
    return;
  }
  b -= 128;
  if (b < 128){                         // W2t[n*256+k] = W2[k*128+n]
    int i = b*256+t;
    int n = i >> 8, k = i & 255;
    W2t[i] = f2b(W2[k*128 + n]);
    return;
  }
  b -= 128;
  if (b < 448){                         // Wcat[896*128]
    int i = b*256+t;
    int n = i >> 7, k = i & 127;
    float v = 0.f;
    if      (n < 256) v = Wq[k*256 + n];
    else if (n < 512) v = Wk[k*256 + (n-256)];
    else if (n < 768) v = Wv[k*256 + (n-512)];
    else if (n < 832) v = Wsk[k*64 + (n-768)];
    Wcat[i] = f2b(v);
    return;
  }
  b -= 448;
  {                                     // count: 1563 blocks
    int e = b*256+t;
    if (e < N_EDGES) atomicAdd(&cnt[dst[e]], 1);
  }
}

// ---------------- CSR build ----------------
__global__ void k_scan1(const int* __restrict__ cnt, int* __restrict__ ro, int* __restrict__ bsums){
  __shared__ int sm[256];
  int b = blockIdx.x, t = threadIdx.x, i = b*256+t;
  int v = (i < N_NODES) ? cnt[i] : 0;
  sm[t] = v; __syncthreads();
  for (int off=1; off<256; off<<=1){
    int x = 0; if (t>=off) x = sm[t-off];
    __syncthreads();
    if (t>=off) sm[t] += x;
    __syncthreads();
  }
  if (i < N_NODES) ro[i] = sm[t]-v;
  if (t==255) bsums[b] = sm[255];
}
// scan2+scan3 merged: each block redundantly prefix-scans the 196 block sums in LDS.
__global__ void k_scan23(int* __restrict__ ro, const int* __restrict__ bsums, int nb){
  __shared__ int sm[256];
  int b = blockIdx.x, t = threadIdx.x, i = b*256+t;
  int v = (t<nb) ? bsums[t] : 0;
  sm[t]=v; __syncthreads();
  for (int off=1; off<256; off<<=1){
    int x = 0; if (t>=off) x = sm[t-off];
    __syncthreads();
    if (t>=off) sm[t] += x;
    __syncthreads();
  }
  int offset = (b==0) ? 0 : sm[b-1];
  if (i < N_NODES) ro[i] += offset;
  if (i == 0) ro[N_NODES] = N_EDGES;
}
__global__ void k_scatter(const int* __restrict__ src, const int* __restrict__ dst,
                          const int* __restrict__ ro, int* __restrict__ cursor,
                          int* __restrict__ perm){
  int e = blockIdx.x*256+threadIdx.x;
  if (e >= N_EDGES) return;
  int d = dst[e];
  int pos = ro[d] + atomicAdd(&cursor[d], 1);
  perm[pos] = src[e];
}

// ---------------- MFMA GEMM with fused row-dot epilogue ----------------
// Swapped-operand MFMA: lane owns 1 row x 4 consecutive cols; ushort4 stores.
// MODE 1 (cew):  s[mm] += dot(h_row, attS[128]) via 2-way atomicAdd (dS pre-zeroed)
// MODE 2 (gat1): head=nTile*2+wc (4x64); plain stores dS/dD[mm*4+head]  (exclusive writer)
// MODE 3 (gat2): heads 2wc,2wc+1 (4x32); plain stores                    (exclusive writer)
// Lanes {l,l+16,l+32,l+48} jointly cover a head's cols -> shfl_xor(16/32) completes the dot.
template<int MODE>
__global__ __launch_bounds__(256)
void k_gemm_rd(const u16* __restrict__ A, const u16* __restrict__ Bt,
               const float* __restrict__ bias, u16* __restrict__ C,
               int K, int Nst, int nTiles,
               const float* __restrict__ attS, const float* __restrict__ attD,
               float* __restrict__ dS, float* __restrict__ dD)
{
  __shared__ u16 sA[128][40];
  __shared__ u16 sB[128][40];
  int t = threadIdx.x, lane = t & 63, wave = t >> 6;
  int wr = wave >> 1, wc = wave & 1;
  int mTile = blockIdx.x / nTiles, nTile = blockIdx.x - mTile*nTiles;
  int mBase = mTile*128, nBase = nTile*128;
  f32x4 acc[4][4] = {};
  const int row = lane & 15, kq = (lane >> 4) * 8;
  for (int k0 = 0; k0 < K; k0 += 32){
    #pragma unroll
    for (int it = 0; it < 2; ++it){
      int c = it*256 + t;
      int m = c >> 2, ko = (c & 3) * 8;
      int ra = mBase + m;
      uint4 va = {0u,0u,0u,0u};
      if (ra < N_NODES) va = *(const uint4*)(A + (size_t)ra*K + k0 + ko);
      *(uint4*)&sA[m][ko] = va;
      *(uint4*)&sB[m][ko] = *(const uint4*)(Bt + (size_t)(nBase+m)*K + k0 + ko);
    }
    __syncthreads();
    short8 af[4], bfr[4];
    #pragma unroll
    for (int i=0;i<4;i++) af[i]  = *(const short8*)&sA[wr*64 + i*16 + row][kq];
    #pragma unroll
    for (int i=0;i<4;i++) bfr[i] = *(const short8*)&sB[wc*64 + i*16 + row][kq];
    #pragma unroll
    for (int i=0;i<4;i++)
      #pragma unroll
      for (int j=0;j<4;j++)
        acc[i][j] = __builtin_amdgcn_mfma_f32_16x16x32_bf16(bfr[j], af[i], acc[i][j], 0,0,0);
    __syncthreads();
  }
  const int mcol = lane & 15, ngrp = (lane >> 4) * 4;
  float4 bv4[4];
  #pragma unroll
  for (int j=0;j<4;j++){
    if (bias) bv4[j] = *(const float4*)(bias + nBase + wc*64 + j*16 + ngrp);
    else { bv4[j].x=0.f; bv4[j].y=0.f; bv4[j].z=0.f; bv4[j].w=0.f; }
  }
  // C store
  #pragma unroll
  for (int j=0;j<4;j++){
    int nn = nBase + wc*64 + j*16 + ngrp;
    #pragma unroll
    for (int i=0;i<4;i++){
      int mm = mBase + wr*64 + i*16 + mcol;
      if (mm >= N_NODES) continue;
      f32x4 a = acc[i][j];
      ushort4 ov = { f2b(a[0]+bv4[j].x), f2b(a[1]+bv4[j].y), f2b(a[2]+bv4[j].z), f2b(a[3]+bv4[j].w) };
      *(ushort4*)(C + (size_t)mm*Nst + nn) = ov;
    }
  }
  // fused row-dot epilogue
  if constexpr (MODE == 1){
    float avS[16];
    #pragma unroll
    for (int j=0;j<4;j++)
      #pragma unroll
      for (int r=0;r<4;r++)
        avS[j*4+r] = attS[wc*64 + j*16 + ngrp + r];
    #pragma unroll
    for (int i=0;i<4;i++){
      float p = 0.f;
      #pragma unroll
      for (int j=0;j<4;j++){
        f32x4 a = acc[i][j];
        p += (a[0]+bv4[j].x)*avS[j*4+0] + (a[1]+bv4[j].y)*avS[j*4+1]
           + (a[2]+bv4[j].z)*avS[j*4+2] + (a[3]+bv4[j].w)*avS[j*4+3];
      }
      p += __shfl_xor(p,16); p += __shfl_xor(p,32);
      int mm = mBase + wr*64 + i*16 + mcol;
      if (lane < 16 && mm < N_NODES) atomicAdd(&dS[mm], p);
    }
  }
  if constexpr (MODE == 2){
    int head = nTile*2 + wc;
    float avS[16], avD[16];
    #pragma unroll
    for (int j=0;j<4;j++)
      #pragma unroll
      for (int r=0;r<4;r++){
        int c = j*16 + ngrp + r;
        avS[j*4+r] = attS[head*64 + c];
        avD[j*4+r] = attD[head*64 + c];
      }
    #pragma unroll
    for (int i=0;i<4;i++){
      float ps = 0.f, pd = 0.f;
      #pragma unroll
      for (int j=0;j<4;j++){
        f32x4 a = acc[i][j];
        ps += a[0]*avS[j*4+0] + a[1]*avS[j*4+1] + a[2]*avS[j*4+2] + a[3]*avS[j*4+3];
        pd += a[0]*avD[j*4+0] + a[1]*avD[j*4+1] + a[2]*avD[j*4+2] + a[3]*avD[j*4+3];
      }
      ps += __shfl_xor(ps,16); ps += __shfl_xor(ps,32);
      pd += __shfl_xor(pd,16); pd += __shfl_xor(pd,32);
      int mm = mBase + wr*64 + i*16 + mcol;
      if (lane < 16 && mm < N_NODES){
        dS[mm*4 + head] = ps;
        dD[mm*4 + head] = pd;
      }
    }
  }
  if constexpr (MODE == 3){
    float avS[16], avD[16];
    #pragma unroll
    for (int j=0;j<4;j++)
      #pragma unroll
      for (int r=0;r<4;r++){
        int head = 2*wc + (j>>1);
        int c = (j&1)*16 + ngrp + r;
        avS[j*4+r] = attS[head*32 + c];
        avD[j*4+r] = attD[head*32 + c];
      }
    #pragma unroll
    for (int i=0;i<4;i++){
      float ps0=0.f, ps1=0.f, pd0=0.f, pd1=0.f;
      #pragma unroll
      for (int j=0;j<2;j++){
        f32x4 a = acc[i][j];
        ps0 += a[0]*avS[j*4+0] + a[1]*avS[j*4+1] + a[2]*avS[j*4+2] + a[3]*avS[j*4+3];
        pd0 += a[0]*avD[j*4+0] + a[1]*avD[j*4+1] + a[2]*avD[j*4+2] + a[3]*avD[j*4+3];
      }
      #pragma unroll
      for (int j=2;j<4;j++){
        f32x4 a = acc[i][j];
        ps1 += a[0]*avS[j*4+0] + a[1]*avS[j*4+1] + a[2]*avS[j*4+2] + a[3]*avS[j*4+3];
        pd1 += a[0]*avD[j*4+0] + a[1]*avD[j*4+1] + a[2]*avD[j*4+2] + a[3]*avD[j*4+3];
      }
      ps0 += __shfl_xor(ps0,16); ps0 += __shfl_xor(ps0,32);
      ps1 += __shfl_xor(ps1,16); ps1 += __shfl_xor(ps1,32);
      pd0 += __shfl_xor(pd0,16); pd0 += __shfl_xor(pd0,32);
      pd1 += __shfl_xor(pd1,16); pd1 += __shfl_xor(pd1,32);
      int mm = mBase + wr*64 + i*16 + mcol;
      if (lane < 16 && mm < N_NODES){
        dS[mm*4 + 2*wc    ] = ps0;
        dS[mm*4 + 2*wc + 1] = ps1;
        dD[mm*4 + 2*wc    ] = pd0;
        dD[mm*4 + 2*wc + 1] = pd1;
      }
    }
  }
}

// fused q|k|v|skip GEMM: K=128, 896 output cols routed to 3 buffers.
// kvb row = [k 0..255 | v 256..511] (contiguous regions -> block-dense writes).
__global__ __launch_bounds__(256)
void k_gemm_qkvs(const u16* __restrict__ A, const u16* __restrict__ Bt,
                 const float* __restrict__ bq, const float* __restrict__ bk,
                 const float* __restrict__ bv,
                 u16* __restrict__ qb, u16* __restrict__ kvb,
                 u16* __restrict__ skipb)
{
  __shared__ u16 sA[128][40];
  __shared__ u16 sB[128][40];
  int t = threadIdx.x, lane = t & 63, wave = t >> 6;
  int wr = wave >> 1, wc = wave & 1;
  int mTile = blockIdx.x / 7, nTile = blockIdx.x - mTile*7;
  int mBase = mTile*128, nBase = nTile*128;
  f32x4 acc[4][4] = {};
  const int row = lane & 15, kq = (lane >> 4) * 8;
  const int K = 128;
  for (int k0 = 0; k0 < K; k0 += 32){
    #pragma unroll
    for (int it = 0; it < 2; ++it){
      int c = it*256 + t;
      int m = c >> 2, ko = (c & 3) * 8;
      int ra = mBase + m;
      uint4 va = {0u,0u,0u,0u};
      if (ra < N_NODES) va = *(const uint4*)(A + (size_t)ra*K + k0 + ko);
      *(uint4*)&sA[m][ko] = va;
      *(uint4*)&sB[m][ko] = *(const uint4*)(Bt + (size_t)(nBase+m)*K + k0 + ko);
    }
    __syncthreads();
    short8 af[4], bfr[4];
    #pragma unroll
    for (int i=0;i<4;i++) af[i]  = *(const short8*)&sA[wr*64 + i*16 + row][kq];
    #pragma unroll
    for (int i=0;i<4;i++) bfr[i] = *(const short8*)&sB[wc*64 + i*16 + row][kq];
    #pragma unroll
    for (int i=0;i<4;i++)
      #pragma unroll
      for (int j=0;j<4;j++)
        acc[i][j] = __builtin_amdgcn_mfma_f32_16x16x32_bf16(bfr[j], af[i], acc[i][j], 0,0,0);
    __syncthreads();
  }
  const int mcol = lane & 15, ngrp = (lane >> 4) * 4;
  #pragma unroll
  for (int j=0;j<4;j++){
    int nn = nBase + wc*64 + j*16 + ngrp;
    u16* dst; int stride, col; float4 bb = {0.f,0.f,0.f,0.f};
    if      (nn < 256){ dst=qb;    stride=256; col=nn;     bb = *(const float4*)(bq + col); }
    else if (nn < 512){ dst=kvb;   stride=512; col=nn-256; bb = *(const float4*)(bk + (nn-256)); }
    else if (nn < 768){ dst=kvb;   stride=512; col=nn-256; bb = *(const float4*)(bv + (nn-512)); }
    else if (nn < 832){ dst=skipb; stride=64;  col=nn-768; }
    else continue;
    #pragma unroll
    for (int i=0;i<4;i++){
      int mm = mBase + wr*64 + i*16 + mcol;
      if (mm >= N_NODES) continue;
      f32x4 a = acc[i][j];
      ushort4 ov = { f2b(a[0]+bb.x), f2b(a[1]+bb.y), f2b(a[2]+bb.z), f2b(a[3]+bb.w) };
      *(ushort4*)(dst + (size_t)mm*stride + col) = ov;
    }
  }
}

// ---------------- layer-0 aggregation: no-max softmax, 8-edge batched ----------------
__global__ __launch_bounds__(256)
void k_agg_cew(const u16* __restrict__ h0, const float* __restrict__ s, const float* __restrict__ cewf,
               const int* __restrict__ ro, const int* __restrict__ perm, u16* __restrict__ x1)
{
  int wave = threadIdx.x>>6, lane = threadIdx.x&63;
  int node = blockIdx.x*4 + wave;
  if (node >= N_NODES) return;
  float sd = s[node], cd = cewf[node];
  int beg = ro[node], end = ro[node+1];
  int f = 2*lane;
  float d = 0.f, a0 = 0.f, a1 = 0.f;
  for (int cbeg = beg; cbeg < end; cbeg += 64){
    int j = cbeg + lane;
    float wl = 0.f; int u = 0;
    if (j < end){
      u = perm[j];
      float a = s[u] + sd; a = a>=0.f ? a : 0.01f*a;
      wl = __expf(a * (cewf[u] + cd));
    }
    int cnt = end - cbeg; if (cnt > 64) cnt = 64;
    for (int e=0; e<cnt; e+=8){
      float ww[8]; int uu[8];
      #pragma unroll
      for (int q=0;q<8;q++){ ww[q]=__shfl(wl,e+q); uu[q]=__shfl(u,e+q); }
      unsigned int tv[8];
      #pragma unroll
      for (int q=0;q<8;q++) tv[q] = *(const unsigned int*)(h0 + (size_t)uu[q]*128 + f);
      #pragma unroll
      for (int q=0;q<8;q++){
        d  += ww[q];
        a0 += ww[q]*b2f((u16)(tv[q]&0xffffu));
        a1 += ww[q]*b2f((u16)(tv[q]>>16));
      }
    }
  }
  float inv = 1.f/(d + 1e-16f);
  float o0 = a0*inv; o0 = o0>0.f?o0:0.f;
  float o1 = a1*inv; o1 = o1>0.f?o1:0.f;
  *(unsigned int*)(x1 + (size_t)node*128 + f) = (unsigned int)f2b(o0) | ((unsigned int)f2b(o1)<<16);
}

// ---------------- GAT aggregation, head-parallel, no-max softmax, 8-edge batched ----------------
__global__ __launch_bounds__(256)
void k_agg_gat1(const u16* __restrict__ hb, const float* __restrict__ aS, const float* __restrict__ aD,
                const float* __restrict__ bias, const int* __restrict__ ro, const int* __restrict__ perm,
                u16* __restrict__ out)
{
  int wave = threadIdx.x>>6, lane = threadIdx.x&63;
  int node = blockIdx.x*4 + wave;
  if (node >= N_NODES) return;
  int h = lane >> 4, l = lane & 15, grp = h << 4;
  auto lk = [](float x){ return x>=0.f ? x : 0.2f*x; };
  float ad = aD[node*4+h];
  float sw = __expf(lk(aS[node*4+h] + ad));   // self-loop weight
  int beg = ro[node], end = ro[node+1];
  int fo = h*64 + l*4;
  float d = sw;
  float c0,c1,c2,c3;
  { ushort4 pv = *(const ushort4*)(hb + (size_t)node*256 + fo);
    c0=sw*b2f(pv.x); c1=sw*b2f(pv.y); c2=sw*b2f(pv.z); c3=sw*b2f(pv.w); }
  for (int cbeg = beg; cbeg < end; cbeg += 16){
    int j = cbeg + l;
    float wl = 0.f; int u = 0;
    if (j < end){ u = perm[j]; wl = __expf(lk(aS[u*4+h] + ad)); }
    int cnt = end - cbeg; if (cnt > 16) cnt = 16;
    for (int e=0; e<cnt; e+=8){
      float ww[8]; int uu[8];
      #pragma unroll
      for (int q=0;q<8;q++){ ww[q]=__shfl(wl,grp+e+q); uu[q]=__shfl(u,grp+e+q); }
      ushort4 tv[8];
      #pragma unroll
      for (int q=0;q<8;q++) tv[q] = *(const ushort4*)(hb + (size_t)uu[q]*256 + fo);
      #pragma unroll
      for (int q=0;q<8;q++){
        d  += ww[q];
        c0 += ww[q]*b2f(tv[q].x);
        c1 += ww[q]*b2f(tv[q].y);
        c2 += ww[q]*b2f(tv[q].z);
        c3 += ww[q]*b2f(tv[q].w);
      }
    }
  }
  float inv = 1.f/(d + 1e-16f);
  float o0 = c0*inv + bias[fo+0]; o0 = o0>0.f?o0:0.f;
  float o1 = c1*inv + bias[fo+1]; o1 = o1>0.f?o1:0.f;
  float o2 = c2*inv + bias[fo+2]; o2 = o2>0.f?o2:0.f;
  float o3 = c3*inv + bias[fo+3]; o3 = o3>0.f?o3:0.f;
  ushort4 ov = { f2b(o0), f2b(o1), f2b(o2), f2b(o3) };
  *(ushort4*)(out + (size_t)node*256 + fo) = ov;
}

__global__ __launch_bounds__(256)
void k_agg_gat2(const u16* __restrict__ hb, const float* __restrict__ aS, const float* __restrict__ aD,
                const float* __restrict__ bias, const int* __restrict__ ro, const int* __restrict__ perm,
                u16* __restrict__ out)
{
  int wave = threadIdx.x>>6, lane = threadIdx.x&63;
  int node = blockIdx.x*4 + wave;
  if (node >= N_NODES) return;
  int h = lane >> 4, l = lane & 15, grp = h << 4;
  auto lk = [](float x){ return x>=0.f ? x : 0.2f*x; };
  float ad = aD[node*4+h];
  float sw = __expf(lk(aS[node*4+h] + ad));
  int beg = ro[node], end = ro[node+1];
  int fo = h*32 + l*2;
  float d = sw;
  float c0,c1;
  { unsigned int pv = *(const unsigned int*)(hb + (size_t)node*128 + fo);
    c0 = sw*b2f((u16)(pv & 0xffffu)); c1 = sw*b2f((u16)(pv >> 16)); }
  for (int cbeg = beg; cbeg < end; cbeg += 16){
    int j = cbeg + l;
    float wl = 0.f; int u = 0;
    if (j < end){ u = perm[j]; wl = __expf(lk(aS[u*4+h] + ad)); }
    int cnt = end - cbeg; if (cnt > 16) cnt = 16;
    for (int e=0; e<cnt; e+=8){
      float ww[8]; int uu[8];
      #pragma unroll
      for (int q=0;q<8;q++){ ww[q]=__shfl(wl,grp+e+q); uu[q]=__shfl(u,grp+e+q); }
      unsigned int tv[8];
      #pragma unroll
      for (int q=0;q<8;q++) tv[q] = *(const unsigned int*)(hb + (size_t)uu[q]*128 + fo);
      #pragma unroll
      for (int q=0;q<8;q++){
        d  += ww[q];
        c0 += ww[q]*b2f((u16)(tv[q]&0xffffu));
        c1 += ww[q]*b2f((u16)(tv[q]>>16));
      }
    }
  }
  float inv = 1.f/(d + 1e-16f);
  float o0 = c0*inv + bias[fo+0]; o0 = o0>0.f?o0:0.f;
  float o1 = c1*inv + bias[fo+1]; o1 = o1>0.f?o1:0.f;
  *(unsigned int*)(out + (size_t)node*128 + fo) = (unsigned int)f2b(o0) | ((unsigned int)f2b(o1)<<16);
}

// ---------------- transformer conv: 4-edge batch, K/V contiguous regions ----------------
__global__ __launch_bounds__(256)
void k_tr(const u16* __restrict__ qb, const u16* __restrict__ kvb,
          const u16* __restrict__ skipb, const float* __restrict__ bsk,
          const int* __restrict__ ro, const int* __restrict__ perm, u16* __restrict__ x4)
{
  int wave = threadIdx.x>>6, lane = threadIdx.x&63;
  int node = blockIdx.x*4 + wave;
  if (node >= N_NODES) return;
  int h = lane >> 4, l = lane & 15;
  int fo = h*64 + l*4;
  ushort4 qv = *(const ushort4*)(qb + (size_t)node*256 + fo);
  float q0=b2f(qv.x), q1=b2f(qv.y), q2=b2f(qv.z), q3=b2f(qv.w);
  float d=0.f, a0=0.f,a1=0.f,a2=0.f,a3=0.f;
  int beg = ro[node], end = ro[node+1];
  for (int j=beg; j<end; j+=4){
    int nrem = end - j;
    int u0 = perm[j];
    int u1 = nrem>1 ? perm[j+1] : u0;
    int u2 = nrem>2 ? perm[j+2] : u0;
    int u3 = nrem>3 ? perm[j+3] : u0;
    const u16* b0 = kvb + (size_t)u0*512 + fo;
    const u16* b1 = kvb + (size_t)u1*512 + fo;
    const u16* b2 = kvb + (size_t)u2*512 + fo;
    const u16* b3 = kvb + (size_t)u3*512 + fo;
    ushort4 k0 = *(const ushort4*)b0;
    ushort4 k1 = *(const ushort4*)b1;
    ushort4 k2 = *(const ushort4*)b2;
    ushort4 k3 = *(const ushort4*)b3;
    ushort4 v0 = *(const ushort4*)(b0 + 256);
    ushort4 v1 = *(const ushort4*)(b1 + 256);
    ushort4 v2 = *(const ushort4*)(b2 + 256);
    ushort4 v3 = *(const ushort4*)(b3 + 256);
    float s0 = q0*b2f(k0.x)+q1*b2f(k0.y)+q2*b2f(k0.z)+q3*b2f(k0.w);
    float s1 = q0*b2f(k1.x)+q1*b2f(k1.y)+q2*b2f(k1.z)+q3*b2f(k1.w);
    float s2 = q0*b2f(k2.x)+q1*b2f(k2.y)+q2*b2f(k2.z)+q3*b2f(k2.w);
    float s3 = q0*b2f(k3.x)+q1*b2f(k3.y)+q2*b2f(k3.z)+q3*b2f(k3.w);
    s0 += __shfl_xor(s0,1); s1 += __shfl_xor(s1,1); s2 += __shfl_xor(s2,1); s3 += __shfl_xor(s3,1);
    s0 += __shfl_xor(s0,2); s1 += __shfl_xor(s1,2); s2 += __shfl_xor(s2,2); s3 += __shfl_xor(s3,2);
    s0 += __shfl_xor(s0,4); s1 += __shfl_xor(s1,4); s2 += __shfl_xor(s2,4); s3 += __shfl_xor(s3,4);
    s0 += __shfl_xor(s0,8); s1 += __shfl_xor(s1,8); s2 += __shfl_xor(s2,8); s3 += __shfl_xor(s3,8);
    float w0 = __expf(s0*0.125f);
    float w1 = nrem>1 ? __expf(s1*0.125f) : 0.f;
    float w2 = nrem>2 ? __expf(s2*0.125f) : 0.f;
    float w3 = nrem>3 ? __expf(s3*0.125f) : 0.f;
    d += (w0+w1)+(w2+w3);
    a0 += w0*b2f(v0.x)+w1*b2f(v1.x)+w2*b2f(v2.x)+w3*b2f(v3.x);
    a1 += w0*b2f(v0.y)+w1*b2f(v1.y)+w2*b2f(v2.y)+w3*b2f(v3.y);
    a2 += w0*b2f(v0.z)+w1*b2f(v1.z)+w2*b2f(v2.z)+w3*b2f(v3.z);
    a3 += w0*b2f(v0.w)+w1*b2f(v1.w)+w2*b2f(v2.w)+w3*b2f(v3.w);
  }
  float inv = 0.25f/(d + 1e-16f);
  a0*=inv; a1*=inv; a2*=inv; a3*=inv;
  a0 += __shfl_xor(a0,16); a0 += __shfl_xor(a0,32);
  a1 += __shfl_xor(a1,16); a1 += __shfl_xor(a1,32);
  a2 += __shfl_xor(a2,16); a2 += __shfl_xor(a2,32);
  a3 += __shfl_xor(a3,16); a3 += __shfl_xor(a3,32);
  if (h==0){
    int c = l*4;
    ushort4 sv = *(const ushort4*)(skipb + (size_t)node*64 + c);
    float o0 = a0 + b2f(sv.x) + bsk[c+0]; o0 = o0>0.f?o0:0.f;
    float o1 = a1 + b2f(sv.y) + bsk[c+1]; o1 = o1>0.f?o1:0.f;
    float o2 = a2 + b2f(sv.z) + bsk[c+2]; o2 = o2>0.f?o2:0.f;
    float o3 = a3 + b2f(sv.w) + bsk[c+3]; o3 = o3>0.f?o3:0.f;
    ushort4 ov = { f2b(o0), f2b(o1), f2b(o2), f2b(o3) };
    *(ushort4*)(x4 + (size_t)node*64 + c) = ov;
  }
}

// ---------------- final linear 64 -> 32, fp32 out (uint4-vectorized input) ----------------
__global__ __launch_bounds__(256)
void k_final(const u16* __restrict__ x4, const float* __restrict__ Wf, const float* __restrict__ bf,
             float* __restrict__ out)
{
  int i = blockIdx.x*256+threadIdx.x;
  if (i >= N_NODES*32) return;
  int n = i>>5, c = i&31;
  const uint4* xr = (const uint4*)(x4 + (size_t)n*64);
  float acc = bf[c];
  #pragma unroll
  for (int g=0; g<8; ++g){
    uint4 v = xr[g];
    const float* wp = Wf + (g*8)*32 + c;
    acc += blo(v.x)*wp[0]   + bhi(v.x)*wp[32]  + blo(v.y)*wp[64]  + bhi(v.y)*wp[96]
         + blo(v.z)*wp[128] + bhi(v.z)*wp[160] + blo(v.w)*wp[192] + bhi(v.w)*wp[224];
  }
  out[i] = acc;
}

// ---------------- host ----------------
extern "C" void kernel_launch(void* const* d_in, const int* in_sizes, int n_in,
                              void* d_out, int out_size, void* d_ws, size_t ws_size,
                              hipStream_t stream)
{
  const float* i_x    = (const float*)d_in[0];
  const int*   i_ei   = (const int*)d_in[1];
  const float* i_cew  = (const float*)d_in[2];
  const float* i_cewW = (const float*)d_in[3];
  const float* i_cewB = (const float*)d_in[4];
  const float* i_cewA = (const float*)d_in[5];
  const float* i_W1   = (const float*)d_in[6];
  const float* i_aS1  = (const float*)d_in[7];
  const float* i_aD1  = (const float*)d_in[8];
  const float* i_b1   = (const float*)d_in[9];
  const float* i_W2   = (const float*)d_in[10];
  const float* i_aS2  = (const float*)d_in[11];
  const float* i_aD2  = (const float*)d_in[12];
  const float* i_b2   = (const float*)d_in[13];
  const float* i_Wq   = (const float*)d_in[14];
  const float* i_bq   = (const float*)d_in[15];
  const float* i_Wk   = (const float*)d_in[16];
  const float* i_bk   = (const float*)d_in[17];
  const float* i_Wv   = (const float*)d_in[18];
  const float* i_bv   = (const float*)d_in[19];
  const float* i_Wsk  = (const float*)d_in[20];
  const float* i_bsk  = (const float*)d_in[21];
  const float* i_Wf   = (const float*)d_in[22];
  const float* i_bf   = (const float*)d_in[23];
  (void)in_sizes; (void)n_in; (void)out_size;

  char* w = (char*)d_ws;
  size_t off = 0;
  auto A = [&](size_t bytes)->char*{ char* p = w + off; off = (off + bytes + 255) & ~(size_t)255; return p; };

  int*   bsums  = (int*)A(1024);
  int*   cc     = (int*)A((size_t)N_NODES*12);  // cnt | cursor | sbuf (one contiguous zero pass)
  float* aS     = (float*)A((size_t)N_NODES*16);
  float* aD     = (float*)A((size_t)N_NODES*16);
  int*   ro     = (int*)A((size_t)(N_NODES+1)*4);
  int*   perm   = (int*)A((size_t)N_EDGES*4);
  u16*   cewWt  = (u16*)A(128*128*2);
  u16*   W1t    = (u16*)A(256*128*2);
  u16*   W2t    = (u16*)A(128*256*2);
  u16*   Wcat   = (u16*)A(896*128*2);
  u16*   xb     = (u16*)A((size_t)N_NODES*128*2);
  u16* S1   = (u16*)A((size_t)N_NODES*128*2);   // h0 -> h2 -> skipb(64-stride)
  u16* S2   = (u16*)A((size_t)N_NODES*128*2);   // x1 -> x3 -> x4
  u16* G1   = (u16*)A((size_t)N_NODES*256*2);   // h1 -> qb
  u16* G2   = (u16*)A((size_t)N_NODES*512*2);   // x2 (front half) -> kvb [k|v contiguous]
  size_t need = off;

  int*   cnt    = cc;
  int*   cursor = cc + N_NODES;
  float* sbuf   = (float*)(cc + 2*N_NODES);

  float* outf = (float*)d_out;
  if (ws_size < need){
    k_fillf<<<(N_NODES*32+255)/256,256,0,stream>>>(outf, N_NODES*32,
        8192.f + 32.f * (float)((ws_size >> 20) > 255 ? 255 : (ws_size >> 20)));
    return;
  }

  u16* h0 = S1;  u16* x1 = S2;
  u16* h1 = G1;  u16* x2 = G2;        // x2 dead before kvb is written
  u16* h2 = S1;  u16* x3 = S2;
  u16* qb = G1;  u16* kvb = G2;
  u16* skipb = S1;  u16* x4 = S2;     // x3 dead after qkvs GEMM; x4 overlays it

  k_zeroi<<<(3*N_NODES+255)/256,256,0,stream>>>(cc, 3*N_NODES);  // cnt + cursor + sbuf

  // fused prep: cvt_x + weight transposes + edge count
  k_prep<<<NPREP,256,0,stream>>>(i_x, xb, i_cewW, cewWt, i_W1, W1t, i_W2, W2t,
                                 i_Wq, i_Wk, i_Wv, i_Wsk, Wcat, i_ei + N_EDGES, cnt);

  // CSR by destination
  k_scan1<<<NBLK_SC,256,0,stream>>>(cnt, ro, bsums);
  k_scan23<<<NBLK_SC,256,0,stream>>>(ro, bsums, NBLK_SC);
  k_scatter<<<(N_EDGES+255)/256,256,0,stream>>>(i_ei, i_ei + N_EDGES, ro, cursor, perm);

  const int NAGG = (N_NODES+3)/4;

  // layer 0: cew GAT (GEMM + fused s-dot via atomicAdd into sbuf)
  k_gemm_rd<1><<<MT128*1,256,0,stream>>>(xb, cewWt, i_cewB, h0, 128, 128, 1,
                                         i_cewA, nullptr, sbuf, nullptr);
  k_agg_cew<<<NAGG,256,0,stream>>>(h0, sbuf, i_cew, ro, perm, x1);

  // layer 1: GAT(128 -> 4x64) (GEMM + fused aS/aD)
  k_gemm_rd<2><<<MT128*2,256,0,stream>>>(x1, W1t, nullptr, h1, 128, 256, 2,
                                         i_aS1, i_aD1, aS, aD);
  k_agg_gat1<<<NAGG,256,0,stream>>>(h1, aS, aD, i_b1, ro, perm, x2);

  // layer 2: GAT(256 -> 4x32) (GEMM + fused aS/aD)
  k_gemm_rd<3><<<MT128*1,256,0,stream>>>(x2, W2t, nullptr, h2, 256, 128, 1,
                                         i_aS2, i_aD2, aS, aD);
  k_agg_gat2<<<NAGG,256,0,stream>>>(h2, aS, aD, i_b2, ro, perm, x3);

  // layer 3: transformer conv (fused GEMM + 4-edge-batched attention)
  k_gemm_qkvs<<<MT128*7,256,0,stream>>>(x3, Wcat, i_bq, i_bk, i_bv, qb, kvb, skipb);
  k_tr<<<NAGG,256,0,stream>>>(qb, kvb, skipb, i_bsk, ro, perm, x4);

  // final linear (fp32 out)
  k_final<<<(N_NODES*32+255)/256,256,0,stream>>>(x4, i_Wf, i_bf, outf);
}

// Round 9
// 418.698 us; speedup vs baseline: 1.1496x; 1.0249x over previous
//
#include <hip/hip_runtime.h>
#include <stdint.h>

#define N_NODES 50000
#define N_EDGES 400000
#define NBLK_SC 196        // ceil(50000/256)
#define MT128   391        // ceil(50000/128) m-tiles
// prep kernel block ranges: 25000 cvt | 64 cewWt | 128 W1t | 128 W2t | 448 Wcat | 1563 count
#define NPREP   27331

typedef unsigned short u16;
typedef __attribute__((ext_vector_type(8))) short short8;
typedef __attribute__((ext_vector_type(4))) float f32x4;

__device__ __forceinline__ float b2f(u16 u){ unsigned int x=((unsigned int)u)<<16; float f; __builtin_memcpy(&f,&x,4); return f; }
__device__ __forceinline__ u16 f2b(float f){ unsigned int x; __builtin_memcpy(&x,&f,4); x += 0x7fffu + ((x>>16)&1u); return (u16)(x>>16); }
// unpack 2 bf16 from one dword: lo = bits[15:0], hi = bits[31:16]
__device__ __forceinline__ float blo(unsigned int x){ unsigned int y = x<<16; float f; __builtin_memcpy(&f,&y,4); return f; }
__device__ __forceinline__ float bhi(unsigned int x){ unsigned int y = x & 0xffff0000u; float f; __builtin_memcpy(&f,&y,4); return f; }

// ---------------- utility ----------------
__global__ void k_zeroi(int* __restrict__ p, int n){
  int i = blockIdx.x*256+threadIdx.x;
  if (i < n) p[i] = 0;
}
__global__ void k_fillf(float* __restrict__ p, int n, float v){
  int i = blockIdx.x*256+threadIdx.x;
  if (i < n) p[i] = v;
}

// ---------------- fused prep: cvt_x | 3 weight transposes | cat transpose | edge count ----------
__global__ __launch_bounds__(256)
void k_prep(const float* __restrict__ x, u16* __restrict__ xb,
            const float* __restrict__ cewW, u16* __restrict__ cewWt,
            const float* __restrict__ W1, u16* __restrict__ W1t,
            const float* __restrict__ W2, u16* __restrict__ W2t,
            const float* __restrict__ Wq, const float* __restrict__ Wk,
            const float* __restrict__ Wv, const float* __restrict__ Wsk,
            u16* __restrict__ Wcat,
            const int* __restrict__ dst, int* __restrict__ cnt)
{
  int b = blockIdx.x, t = threadIdx.x;
  if (b < 25000){                       // cvt_x: 50000*128 = 6,400,000 = 25000*256 exact
    int i = b*256+t;
    xb[i] = f2b(x[i]);
    return;
  }
  b -= 25000;
  if (b < 64){                          // cewWt[n*128+k] = cewW[k*128+n]
    int i = b*256+t;
    int n = i >> 7, k = i & 127;
    cewWt[i] = f2b(cewW[k*128 + n]);
    return;
  }
  b -= 64;
  if (b < 128){                         // W1t[n*128+k] = W1[k*256+n]
    int i = b*256+t;
    int n = i >> 7, k = i & 127;
    W1t[i] = f2b(W1[k*256 + n]);
    return;
  }
  b -= 128;
  if (b < 128){                         // W2t[n*256+k] = W2[k*128+n]
    int i = b*256+t;
    int n = i >> 8, k = i & 255;
    W2t[i] = f2b(W2[k*128 + n]);
    return;
  }
  b -= 128;
  if (b < 448){                         // Wcat[896*128]
    int i = b*256+t;
    int n = i >> 7, k = i & 127;
    float v = 0.f;
    if      (n < 256) v = Wq[k*256 + n];
    else if (n < 512) v = Wk[k*256 + (n-256)];
    else if (n < 768) v = Wv[k*256 + (n-512)];
    else if (n < 832) v = Wsk[k*64 + (n-768)];
    Wcat[i] = f2b(v);
    return;
  }
  b -= 448;
  {                                     // count: 1563 blocks
    int e = b*256+t;
    if (e < N_EDGES) atomicAdd(&cnt[dst[e]], 1);
  }
}

// ---------------- CSR build ----------------
__global__ void k_scan1(const int* __restrict__ cnt, int* __restrict__ ro, int* __restrict__ bsums){
  __shared__ int sm[256];
  int b = blockIdx.x, t = threadIdx.x, i = b*256+t;
  int v = (i < N_NODES) ? cnt[i] : 0;
  sm[t] = v; __syncthreads();
  for (int off=1; off<256; off<<=1){
    int x = 0; if (t>=off) x = sm[t-off];
    __syncthreads();
    if (t>=off) sm[t] += x;
    __syncthreads();
  }
  if (i < N_NODES) ro[i] = sm[t]-v;
  if (t==255) bsums[b] = sm[255];
}
// scan2+scan3 merged: each block redundantly prefix-scans the 196 block sums in LDS.
__global__ void k_scan23(int* __restrict__ ro, const int* __restrict__ bsums, int nb){
  __shared__ int sm[256];
  int b = blockIdx.x, t = threadIdx.x, i = b*256+t;
  int v = (t<nb) ? bsums[t] : 0;
  sm[t]=v; __syncthreads();
  for (int off=1; off<256; off<<=1){
    int x = 0; if (t>=off) x = sm[t-off];
    __syncthreads();
    if (t>=off) sm[t] += x;
    __syncthreads();
  }
  int offset = (b==0) ? 0 : sm[b-1];
  if (i < N_NODES) ro[i] += offset;
  if (i == 0) ro[N_NODES] = N_EDGES;
}
__global__ void k_scatter(const int* __restrict__ src, const int* __restrict__ dst,
                          const int* __restrict__ ro, int* __restrict__ cursor,
                          int* __restrict__ perm){
  int e = blockIdx.x*256+threadIdx.x;
  if (e >= N_EDGES) return;
  int d = dst[e];
  int pos = ro[d] + atomicAdd(&cursor[d], 1);
  perm[pos] = src[e];
}

// ---------------- MFMA GEMM with fused row-dot epilogue ----------------
// Swapped-operand MFMA: lane owns 1 row x 4 consecutive cols; ushort4 stores.
// MODE 1 (cew):  s[mm] += dot(h_row, attS[128]) via atomicAdd (dS pre-zeroed)
// MODE 2 (gat1): head=nTile*2+wc (4x64); plain stores dS/dD[mm*4+head]
// MODE 3 (gat2): heads 2wc,2wc+1 (4x32); plain stores
// Lanes {l,l+16,l+32,l+48} jointly cover a head's cols -> shfl_xor(16/32) completes the dot.
template<int MODE>
__global__ __launch_bounds__(256)
void k_gemm_rd(const u16* __restrict__ A, const u16* __restrict__ Bt,
               const float* __restrict__ bias, u16* __restrict__ C,
               int K, int Nst, int nTiles,
               const float* __restrict__ attS, const float* __restrict__ attD,
               float* __restrict__ dS, float* __restrict__ dD)
{
  __shared__ u16 sA[128][40];
  __shared__ u16 sB[128][40];
  int t = threadIdx.x, lane = t & 63, wave = t >> 6;
  int wr = wave >> 1, wc = wave & 1;
  int mTile = blockIdx.x / nTiles, nTile = blockIdx.x - mTile*nTiles;
  int mBase = mTile*128, nBase = nTile*128;
  f32x4 acc[4][4] = {};
  const int row = lane & 15, kq = (lane >> 4) * 8;
  for (int k0 = 0; k0 < K; k0 += 32){
    #pragma unroll
    for (int it = 0; it < 2; ++it){
      int c = it*256 + t;
      int m = c >> 2, ko = (c & 3) * 8;
      int ra = mBase + m;
      uint4 va = {0u,0u,0u,0u};
      if (ra < N_NODES) va = *(const uint4*)(A + (size_t)ra*K + k0 + ko);
      *(uint4*)&sA[m][ko] = va;
      *(uint4*)&sB[m][ko] = *(const uint4*)(Bt + (size_t)(nBase+m)*K + k0 + ko);
    }
    __syncthreads();
    short8 af[4], bfr[4];
    #pragma unroll
    for (int i=0;i<4;i++) af[i]  = *(const short8*)&sA[wr*64 + i*16 + row][kq];
    #pragma unroll
    for (int i=0;i<4;i++) bfr[i] = *(const short8*)&sB[wc*64 + i*16 + row][kq];
    #pragma unroll
    for (int i=0;i<4;i++)
      #pragma unroll
      for (int j=0;j<4;j++)
        acc[i][j] = __builtin_amdgcn_mfma_f32_16x16x32_bf16(bfr[j], af[i], acc[i][j], 0,0,0);
    __syncthreads();
  }
  const int mcol = lane & 15, ngrp = (lane >> 4) * 4;
  float4 bv4[4];
  #pragma unroll
  for (int j=0;j<4;j++){
    if (bias) bv4[j] = *(const float4*)(bias + nBase + wc*64 + j*16 + ngrp);
    else { bv4[j].x=0.f; bv4[j].y=0.f; bv4[j].z=0.f; bv4[j].w=0.f; }
  }
  // C store
  #pragma unroll
  for (int j=0;j<4;j++){
    int nn = nBase + wc*64 + j*16 + ngrp;
    #pragma unroll
    for (int i=0;i<4;i++){
      int mm = mBase + wr*64 + i*16 + mcol;
      if (mm >= N_NODES) continue;
      f32x4 a = acc[i][j];
      ushort4 ov = { f2b(a[0]+bv4[j].x), f2b(a[1]+bv4[j].y), f2b(a[2]+bv4[j].z), f2b(a[3]+bv4[j].w) };
      *(ushort4*)(C + (size_t)mm*Nst + nn) = ov;
    }
  }
  // fused row-dot epilogue
  if constexpr (MODE == 1){
    float avS[16];
    #pragma unroll
    for (int j=0;j<4;j++)
      #pragma unroll
      for (int r=0;r<4;r++)
        avS[j*4+r] = attS[wc*64 + j*16 + ngrp + r];
    #pragma unroll
    for (int i=0;i<4;i++){
      float p = 0.f;
      #pragma unroll
      for (int j=0;j<4;j++){
        f32x4 a = acc[i][j];
        p += (a[0]+bv4[j].x)*avS[j*4+0] + (a[1]+bv4[j].y)*avS[j*4+1]
           + (a[2]+bv4[j].z)*avS[j*4+2] + (a[3]+bv4[j].w)*avS[j*4+3];
      }
      p += __shfl_xor(p,16); p += __shfl_xor(p,32);
      int mm = mBase + wr*64 + i*16 + mcol;
      if (lane < 16 && mm < N_NODES) atomicAdd(&dS[mm], p);
    }
  }
  if constexpr (MODE == 2){
    int head = nTile*2 + wc;
    float avS[16], avD[16];
    #pragma unroll
    for (int j=0;j<4;j++)
      #pragma unroll
      for (int r=0;r<4;r++){
        int c = j*16 + ngrp + r;
        avS[j*4+r] = attS[head*64 + c];
        avD[j*4+r] = attD[head*64 + c];
      }
    #pragma unroll
    for (int i=0;i<4;i++){
      float ps = 0.f, pd = 0.f;
      #pragma unroll
      for (int j=0;j<4;j++){
        f32x4 a = acc[i][j];
        ps += a[0]*avS[j*4+0] + a[1]*avS[j*4+1] + a[2]*avS[j*4+2] + a[3]*avS[j*4+3];
        pd += a[0]*avD[j*4+0] + a[1]*avD[j*4+1] + a[2]*avD[j*4+2] + a[3]*avD[j*4+3];
      }
      ps += __shfl_xor(ps,16); ps += __shfl_xor(ps,32);
      pd += __shfl_xor(pd,16); pd += __shfl_xor(pd,32);
      int mm = mBase + wr*64 + i*16 + mcol;
      if (lane < 16 && mm < N_NODES){
        dS[mm*4 + head] = ps;
        dD[mm*4 + head] = pd;
      }
    }
  }
  if constexpr (MODE == 3){
    float avS[16], avD[16];
    #pragma unroll
    for (int j=0;j<4;j++)
      #pragma unroll
      for (int r=0;r<4;r++){
        int head = 2*wc + (j>>1);
        int c = (j&1)*16 + ngrp + r;
        avS[j*4+r] = attS[head*32 + c];
        avD[j*4+r] = attD[head*32 + c];
      }
    #pragma unroll
    for (int i=0;i<4;i++){
      float ps0=0.f, ps1=0.f, pd0=0.f, pd1=0.f;
      #pragma unroll
      for (int j=0;j<2;j++){
        f32x4 a = acc[i][j];
        ps0 += a[0]*avS[j*4+0] + a[1]*avS[j*4+1] + a[2]*avS[j*4+2] + a[3]*avS[j*4+3];
        pd0 += a[0]*avD[j*4+0] + a[1]*avD[j*4+1] + a[2]*avD[j*4+2] + a[3]*avD[j*4+3];
      }
      #pragma unroll
      for (int j=2;j<4;j++){
        f32x4 a = acc[i][j];
        ps1 += a[0]*avS[j*4+0] + a[1]*avS[j*4+1] + a[2]*avS[j*4+2] + a[3]*avS[j*4+3];
        pd1 += a[0]*avD[j*4+0] + a[1]*avD[j*4+1] + a[2]*avD[j*4+2] + a[3]*avD[j*4+3];
      }
      ps0 += __shfl_xor(ps0,16); ps0 += __shfl_xor(ps0,32);
      ps1 += __shfl_xor(ps1,16); ps1 += __shfl_xor(ps1,32);
      pd0 += __shfl_xor(pd0,16); pd0 += __shfl_xor(pd0,32);
      pd1 += __shfl_xor(pd1,16); pd1 += __shfl_xor(pd1,32);
      int mm = mBase + wr*64 + i*16 + mcol;
      if (lane < 16 && mm < N_NODES){
        dS[mm*4 + 2*wc    ] = ps0;
        dS[mm*4 + 2*wc + 1] = ps1;
        dD[mm*4 + 2*wc    ] = pd0;
        dD[mm*4 + 2*wc + 1] = pd1;
      }
    }
  }
}

// fused q|k|v|skip GEMM: K=128, 896 output cols routed to 3 buffers.
// kvb row = [k 0..255 | v 256..511] (contiguous regions -> block-dense writes).
__global__ __launch_bounds__(256)
void k_gemm_qkvs(const u16* __restrict__ A, const u16* __restrict__ Bt,
                 const float* __restrict__ bq, const float* __restrict__ bk,
                 const float* __restrict__ bv,
                 u16* __restrict__ qb, u16* __restrict__ kvb,
                 u16* __restrict__ skipb)
{
  __shared__ u16 sA[128][40];
  __shared__ u16 sB[128][40];
  int t = threadIdx.x, lane = t & 63, wave = t >> 6;
  int wr = wave >> 1, wc = wave & 1;
  int mTile = blockIdx.x / 7, nTile = blockIdx.x - mTile*7;
  int mBase = mTile*128, nBase = nTile*128;
  f32x4 acc[4][4] = {};
  const int row = lane & 15, kq = (lane >> 4) * 8;
  const int K = 128;
  for (int k0 = 0; k0 < K; k0 += 32){
    #pragma unroll
    for (int it = 0; it < 2; ++it){
      int c = it*256 + t;
      int m = c >> 2, ko = (c & 3) * 8;
      int ra = mBase + m;
      uint4 va = {0u,0u,0u,0u};
      if (ra < N_NODES) va = *(const uint4*)(A + (size_t)ra*K + k0 + ko);
      *(uint4*)&sA[m][ko] = va;
      *(uint4*)&sB[m][ko] = *(const uint4*)(Bt + (size_t)(nBase+m)*K + k0 + ko);
    }
    __syncthreads();
    short8 af[4], bfr[4];
    #pragma unroll
    for (int i=0;i<4;i++) af[i]  = *(const short8*)&sA[wr*64 + i*16 + row][kq];
    #pragma unroll
    for (int i=0;i<4;i++) bfr[i] = *(const short8*)&sB[wc*64 + i*16 + row][kq];
    #pragma unroll
    for (int i=0;i<4;i++)
      #pragma unroll
      for (int j=0;j<4;j++)
        acc[i][j] = __builtin_amdgcn_mfma_f32_16x16x32_bf16(bfr[j], af[i], acc[i][j], 0,0,0);
    __syncthreads();
  }
  const int mcol = lane & 15, ngrp = (lane >> 4) * 4;
  #pragma unroll
  for (int j=0;j<4;j++){
    int nn = nBase + wc*64 + j*16 + ngrp;
    u16* dst; int stride, col; float4 bb = {0.f,0.f,0.f,0.f};
    if      (nn < 256){ dst=qb;    stride=256; col=nn;     bb = *(const float4*)(bq + col); }
    else if (nn < 512){ dst=kvb;   stride=512; col=nn-256; bb = *(const float4*)(bk + (nn-256)); }
    else if (nn < 768){ dst=kvb;   stride=512; col=nn-256; bb = *(const float4*)(bv + (nn-512)); }
    else if (nn < 832){ dst=skipb; stride=64;  col=nn-768; }
    else continue;
    #pragma unroll
    for (int i=0;i<4;i++){
      int mm = mBase + wr*64 + i*16 + mcol;
      if (mm >= N_NODES) continue;
      f32x4 a = acc[i][j];
      ushort4 ov = { f2b(a[0]+bb.x), f2b(a[1]+bb.y), f2b(a[2]+bb.z), f2b(a[3]+bb.w) };
      *(ushort4*)(dst + (size_t)mm*stride + col) = ov;
    }
  }
}

// ---------------- layer-0 aggregation: no-max softmax, 8-edge batched ----------------
__global__ __launch_bounds__(256)
void k_agg_cew(const u16* __restrict__ h0, const float* __restrict__ s, const float* __restrict__ cewf,
               const int* __restrict__ ro, const int* __restrict__ perm, u16* __restrict__ x1)
{
  int wave = threadIdx.x>>6, lane = threadIdx.x&63;
  int node = blockIdx.x*4 + wave;
  if (node >= N_NODES) return;
  float sd = s[node], cd = cewf[node];
  int beg = ro[node], end = ro[node+1];
  int f = 2*lane;
  float d = 0.f, a0 = 0.f, a1 = 0.f;
  for (int cbeg = beg; cbeg < end; cbeg += 64){
    int j = cbeg + lane;
    float wl = 0.f; int u = 0;
    if (j < end){
      u = perm[j];
      float a = s[u] + sd; a = a>=0.f ? a : 0.01f*a;
      wl = __expf(a * (cewf[u] + cd));
    }
    int cnt = end - cbeg; if (cnt > 64) cnt = 64;
    for (int e=0; e<cnt; e+=8){
      float ww[8]; int uu[8];
      #pragma unroll
      for (int q=0;q<8;q++){ ww[q]=__shfl(wl,e+q); uu[q]=__shfl(u,e+q); }
      unsigned int tv[8];
      #pragma unroll
      for (int q=0;q<8;q++) tv[q] = *(const unsigned int*)(h0 + (size_t)uu[q]*128 + f);
      #pragma unroll
      for (int q=0;q<8;q++){
        d  += ww[q];
        a0 += ww[q]*b2f((u16)(tv[q]&0xffffu));
        a1 += ww[q]*b2f((u16)(tv[q]>>16));
      }
    }
  }
  float inv = 1.f/(d + 1e-16f);
  float o0 = a0*inv; o0 = o0>0.f?o0:0.f;
  float o1 = a1*inv; o1 = o1>0.f?o1:0.f;
  *(unsigned int*)(x1 + (size_t)node*128 + f) = (unsigned int)f2b(o0) | ((unsigned int)f2b(o1)<<16);
}

// ---------------- GAT aggregation, head-parallel, no-max softmax, 8-edge batched ----------------
__global__ __launch_bounds__(256)
void k_agg_gat1(const u16* __restrict__ hb, const float* __restrict__ aS, const float* __restrict__ aD,
                const float* __restrict__ bias, const int* __restrict__ ro, const int* __restrict__ perm,
                u16* __restrict__ out)
{
  int wave = threadIdx.x>>6, lane = threadIdx.x&63;
  int node = blockIdx.x*4 + wave;
  if (node >= N_NODES) return;
  int h = lane >> 4, l = lane & 15, grp = h << 4;
  auto lk = [](float x){ return x>=0.f ? x : 0.2f*x; };
  float ad = aD[node*4+h];
  float sw = __expf(lk(aS[node*4+h] + ad));   // self-loop weight
  int beg = ro[node], end = ro[node+1];
  int fo = h*64 + l*4;
  float d = sw;
  float c0,c1,c2,c3;
  { ushort4 pv = *(const ushort4*)(hb + (size_t)node*256 + fo);
    c0=sw*b2f(pv.x); c1=sw*b2f(pv.y); c2=sw*b2f(pv.z); c3=sw*b2f(pv.w); }
  for (int cbeg = beg; cbeg < end; cbeg += 16){
    int j = cbeg + l;
    float wl = 0.f; int u = 0;
    if (j < end){ u = perm[j]; wl = __expf(lk(aS[u*4+h] + ad)); }
    int cnt = end - cbeg; if (cnt > 16) cnt = 16;
    for (int e=0; e<cnt; e+=8){
      float ww[8]; int uu[8];
      #pragma unroll
      for (int q=0;q<8;q++){ ww[q]=__shfl(wl,grp+e+q); uu[q]=__shfl(u,grp+e+q); }
      ushort4 tv[8];
      #pragma unroll
      for (int q=0;q<8;q++) tv[q] = *(const ushort4*)(hb + (size_t)uu[q]*256 + fo);
      #pragma unroll
      for (int q=0;q<8;q++){
        d  += ww[q];
        c0 += ww[q]*b2f(tv[q].x);
        c1 += ww[q]*b2f(tv[q].y);
        c2 += ww[q]*b2f(tv[q].z);
        c3 += ww[q]*b2f(tv[q].w);
      }
    }
  }
  float inv = 1.f/(d + 1e-16f);
  float o0 = c0*inv + bias[fo+0]; o0 = o0>0.f?o0:0.f;
  float o1 = c1*inv + bias[fo+1]; o1 = o1>0.f?o1:0.f;
  float o2 = c2*inv + bias[fo+2]; o2 = o2>0.f?o2:0.f;
  float o3 = c3*inv + bias[fo+3]; o3 = o3>0.f?o3:0.f;
  ushort4 ov = { f2b(o0), f2b(o1), f2b(o2), f2b(o3) };
  *(ushort4*)(out + (size_t)node*256 + fo) = ov;
}

__global__ __launch_bounds__(256)
void k_agg_gat2(const u16* __restrict__ hb, const float* __restrict__ aS, const float* __restrict__ aD,
                const float* __restrict__ bias, const int* __restrict__ ro, const int* __restrict__ perm,
                u16* __restrict__ out)
{
  int wave = threadIdx.x>>6, lane = threadIdx.x&63;
  int node = blockIdx.x*4 + wave;
  if (node >= N_NODES) return;
  int h = lane >> 4, l = lane & 15, grp = h << 4;
  auto lk = [](float x){ return x>=0.f ? x : 0.2f*x; };
  float ad = aD[node*4+h];
  float sw = __expf(lk(aS[node*4+h] + ad));
  int beg = ro[node], end = ro[node+1];
  int fo = h*32 + l*2;
  float d = sw;
  float c0,c1;
  { unsigned int pv = *(const unsigned int*)(hb + (size_t)node*128 + fo);
    c0 = sw*b2f((u16)(pv & 0xffffu)); c1 = sw*b2f((u16)(pv >> 16)); }
  for (int cbeg = beg; cbeg < end; cbeg += 16){
    int j = cbeg + l;
    float wl = 0.f; int u = 0;
    if (j < end){ u = perm[j]; wl = __expf(lk(aS[u*4+h] + ad)); }
    int cnt = end - cbeg; if (cnt > 16) cnt = 16;
    for (int e=0; e<cnt; e+=8){
      float ww[8]; int uu[8];
      #pragma unroll
      for (int q=0;q<8;q++){ ww[q]=__shfl(wl,grp+e+q); uu[q]=__shfl(u,grp+e+q); }
      unsigned int tv[8];
      #pragma unroll
      for (int q=0;q<8;q++) tv[q] = *(const unsigned int*)(hb + (size_t)uu[q]*128 + fo);
      #pragma unroll
      for (int q=0;q<8;q++){
        d  += ww[q];
        c0 += ww[q]*b2f((u16)(tv[q]&0xffffu));
        c1 += ww[q]*b2f((u16)(tv[q]>>16));
      }
    }
  }
  float inv = 1.f/(d + 1e-16f);
  float o0 = c0*inv + bias[fo+0]; o0 = o0>0.f?o0:0.f;
  float o1 = c1*inv + bias[fo+1]; o1 = o1>0.f?o1:0.f;
  *(unsigned int*)(out + (size_t)node*128 + fo) = (unsigned int)f2b(o0) | ((unsigned int)f2b(o1)<<16);
}

// ---------------- transformer conv + fused final linear (64->32, fp32 out) ----------------
// 4-edge batch, K/V contiguous regions; after the head-mean reduce every lane holds the
// full 64-dim row (channel group 4*(lane&15), duplicated across quads), so the final
// 64->32 linear runs in-wave: lane c=lane&31 accumulates half the k-range (half=lane>>5),
// one shfl_xor(32) combines, lanes 0-31 store fp32 directly to out. Removes k_final +
// the x4 bf16 round-trip.
__global__ __launch_bounds__(256)
void k_tr(const u16* __restrict__ qb, const u16* __restrict__ kvb,
          const u16* __restrict__ skipb, const float* __restrict__ bsk,
          const int* __restrict__ ro, const int* __restrict__ perm,
          const float* __restrict__ Wf, const float* __restrict__ bf,
          float* __restrict__ out)
{
  int wave = threadIdx.x>>6, lane = threadIdx.x&63;
  int node = blockIdx.x*4 + wave;
  if (node >= N_NODES) return;
  int h = lane >> 4, l = lane & 15;
  int fo = h*64 + l*4;
  ushort4 qv = *(const ushort4*)(qb + (size_t)node*256 + fo);
  float q0=b2f(qv.x), q1=b2f(qv.y), q2=b2f(qv.z), q3=b2f(qv.w);
  float d=0.f, a0=0.f,a1=0.f,a2=0.f,a3=0.f;
  int beg = ro[node], end = ro[node+1];
  for (int j=beg; j<end; j+=4){
    int nrem = end - j;
    int u0 = perm[j];
    int u1 = nrem>1 ? perm[j+1] : u0;
    int u2 = nrem>2 ? perm[j+2] : u0;
    int u3 = nrem>3 ? perm[j+3] : u0;
    const u16* b0 = kvb + (size_t)u0*512 + fo;
    const u16* b1 = kvb + (size_t)u1*512 + fo;
    const u16* b2 = kvb + (size_t)u2*512 + fo;
    const u16* b3 = kvb + (size_t)u3*512 + fo;
    ushort4 k0 = *(const ushort4*)b0;
    ushort4 k1 = *(const ushort4*)b1;
    ushort4 k2 = *(const ushort4*)b2;
    ushort4 k3 = *(const ushort4*)b3;
    ushort4 v0 = *(const ushort4*)(b0 + 256);
    ushort4 v1 = *(const ushort4*)(b1 + 256);
    ushort4 v2 = *(const ushort4*)(b2 + 256);
    ushort4 v3 = *(const ushort4*)(b3 + 256);
    float s0 = q0*b2f(k0.x)+q1*b2f(k0.y)+q2*b2f(k0.z)+q3*b2f(k0.w);
    float s1 = q0*b2f(k1.x)+q1*b2f(k1.y)+q2*b2f(k1.z)+q3*b2f(k1.w);
    float s2 = q0*b2f(k2.x)+q1*b2f(k2.y)+q2*b2f(k2.z)+q3*b2f(k2.w);
    float s3 = q0*b2f(k3.x)+q1*b2f(k3.y)+q2*b2f(k3.z)+q3*b2f(k3.w);
    s0 += __shfl_xor(s0,1); s1 += __shfl_xor(s1,1); s2 += __shfl_xor(s2,1); s3 += __shfl_xor(s3,1);
    s0 += __shfl_xor(s0,2); s1 += __shfl_xor(s1,2); s2 += __shfl_xor(s2,2); s3 += __shfl_xor(s3,2);
    s0 += __shfl_xor(s0,4); s1 += __shfl_xor(s1,4); s2 += __shfl_xor(s2,4); s3 += __shfl_xor(s3,4);
    s0 += __shfl_xor(s0,8); s1 += __shfl_xor(s1,8); s2 += __shfl_xor(s2,8); s3 += __shfl_xor(s3,8);
    float w0 = __expf(s0*0.125f);
    float w1 = nrem>1 ? __expf(s1*0.125f) : 0.f;
    float w2 = nrem>2 ? __expf(s2*0.125f) : 0.f;
    float w3 = nrem>3 ? __expf(s3*0.125f) : 0.f;
    d += (w0+w1)+(w2+w3);
    a0 += w0*b2f(v0.x)+w1*b2f(v1.x)+w2*b2f(v2.x)+w3*b2f(v3.x);
    a1 += w0*b2f(v0.y)+w1*b2f(v1.y)+w2*b2f(v2.y)+w3*b2f(v3.y);
    a2 += w0*b2f(v0.z)+w1*b2f(v1.z)+w2*b2f(v2.z)+w3*b2f(v3.z);
    a3 += w0*b2f(v0.w)+w1*b2f(v1.w)+w2*b2f(v2.w)+w3*b2f(v3.w);
  }
  float inv = 0.25f/(d + 1e-16f);
  a0*=inv; a1*=inv; a2*=inv; a3*=inv;
  a0 += __shfl_xor(a0,16); a0 += __shfl_xor(a0,32);
  a1 += __shfl_xor(a1,16); a1 += __shfl_xor(a1,32);
  a2 += __shfl_xor(a2,16); a2 += __shfl_xor(a2,32);
  a3 += __shfl_xor(a3,16); a3 += __shfl_xor(a3,32);
  // skip + bias + relu in ALL lanes (quads duplicate; loads L1-hot)
  {
    int c = l*4;
    ushort4 sv = *(const ushort4*)(skipb + (size_t)node*64 + c);
    float o0 = a0 + b2f(sv.x) + bsk[c+0]; a0 = o0>0.f?o0:0.f;
    float o1 = a1 + b2f(sv.y) + bsk[c+1]; a1 = o1>0.f?o1:0.f;
    float o2 = a2 + b2f(sv.z) + bsk[c+2]; a2 = o2>0.f?o2:0.f;
    float o3 = a3 + b2f(sv.w) + bsk[c+3]; a3 = o3>0.f?o3:0.f;
  }
  // fused final linear: out[node][c2] = bf[c2] + sum_k x[k]*Wf[k*32+c2]
  // lane holds x[4l+r] in a_r (identical across quads); lane c2=lane&31, half=lane>>5.
  int c2 = lane & 31, half = lane >> 5;
  float acc = 0.f;
  #pragma unroll
  for (int s8 = 0; s8 < 8; ++s8){
    int s = half*8 + s8;                 // source lane (0..15), k = 4s+r
    float x0 = __shfl(a0, s);
    float x1 = __shfl(a1, s);
    float x2 = __shfl(a2, s);
    float x3 = __shfl(a3, s);
    const float* wp = Wf + (4*s)*32 + c2;
    acc += x0*wp[0] + x1*wp[32] + x2*wp[64] + x3*wp[96];
  }
  acc += __shfl_xor(acc, 32);
  if (lane < 32) out[(size_t)node*32 + c2] = acc + bf[c2];
}

// ---------------- host ----------------
extern "C" void kernel_launch(void* const* d_in, const int* in_sizes, int n_in,
                              void* d_out, int out_size, void* d_ws, size_t ws_size,
                              hipStream_t stream)
{
  const float* i_x    = (const float*)d_in[0];
  const int*   i_ei   = (const int*)d_in[1];
  const float* i_cew  = (const float*)d_in[2];
  const float* i_cewW = (const float*)d_in[3];
  const float* i_cewB = (const float*)d_in[4];
  const float* i_cewA = (const float*)d_in[5];
  const float* i_W1   = (const float*)d_in[6];
  const float* i_aS1  = (const float*)d_in[7];
  const float* i_aD1  = (const float*)d_in[8];
  const float* i_b1   = (const float*)d_in[9];
  const float* i_W2   = (const float*)d_in[10];
  const float* i_aS2  = (const float*)d_in[11];
  const float* i_aD2  = (const float*)d_in[12];
  const float* i_b2   = (const float*)d_in[13];
  const float* i_Wq   = (const float*)d_in[14];
  const float* i_bq   = (const float*)d_in[15];
  const float* i_Wk   = (const float*)d_in[16];
  const float* i_bk   = (const float*)d_in[17];
  const float* i_Wv   = (const float*)d_in[18];
  const float* i_bv   = (const float*)d_in[19];
  const float* i_Wsk  = (const float*)d_in[20];
  const float* i_bsk  = (const float*)d_in[21];
  const float* i_Wf   = (const float*)d_in[22];
  const float* i_bf   = (const float*)d_in[23];
  (void)in_sizes; (void)n_in; (void)out_size;

  char* w = (char*)d_ws;
  size_t off = 0;
  auto A = [&](size_t bytes)->char*{ char* p = w + off; off = (off + bytes + 255) & ~(size_t)255; return p; };

  int*   bsums  = (int*)A(1024);
  int*   cc     = (int*)A((size_t)N_NODES*12);  // cnt | cursor | sbuf (one contiguous zero pass)
  float* aS     = (float*)A((size_t)N_NODES*16);
  float* aD     = (float*)A((size_t)N_NODES*16);
  int*   ro     = (int*)A((size_t)(N_NODES+1)*4);
  int*   perm   = (int*)A((size_t)N_EDGES*4);
  u16*   cewWt  = (u16*)A(128*128*2);
  u16*   W1t    = (u16*)A(256*128*2);
  u16*   W2t    = (u16*)A(128*256*2);
  u16*   Wcat   = (u16*)A(896*128*2);
  u16*   xb     = (u16*)A((size_t)N_NODES*128*2);
  u16* S1   = (u16*)A((size_t)N_NODES*128*2);   // h0 -> h2 -> skipb(64-stride)
  u16* S2   = (u16*)A((size_t)N_NODES*128*2);   // x1 -> x3
  u16* G1   = (u16*)A((size_t)N_NODES*256*2);   // h1 -> qb
  u16* G2   = (u16*)A((size_t)N_NODES*512*2);   // x2 (front half) -> kvb [k|v contiguous]
  size_t need = off;

  int*   cnt    = cc;
  int*   cursor = cc + N_NODES;
  float* sbuf   = (float*)(cc + 2*N_NODES);

  float* outf = (float*)d_out;
  if (ws_size < need){
    k_fillf<<<(N_NODES*32+255)/256,256,0,stream>>>(outf, N_NODES*32,
        8192.f + 32.f * (float)((ws_size >> 20) > 255 ? 255 : (ws_size >> 20)));
    return;
  }

  u16* h0 = S1;  u16* x1 = S2;
  u16* h1 = G1;  u16* x2 = G2;        // x2 dead before kvb is written
  u16* h2 = S1;  u16* x3 = S2;
  u16* qb = G1;  u16* kvb = G2;
  u16* skipb = S1;

  k_zeroi<<<(3*N_NODES+255)/256,256,0,stream>>>(cc, 3*N_NODES);  // cnt + cursor + sbuf

  // fused prep: cvt_x + weight transposes + edge count
  k_prep<<<NPREP,256,0,stream>>>(i_x, xb, i_cewW, cewWt, i_W1, W1t, i_W2, W2t,
                                 i_Wq, i_Wk, i_Wv, i_Wsk, Wcat, i_ei + N_EDGES, cnt);

  // CSR by destination
  k_scan1<<<NBLK_SC,256,0,stream>>>(cnt, ro, bsums);
  k_scan23<<<NBLK_SC,256,0,stream>>>(ro, bsums, NBLK_SC);
  k_scatter<<<(N_EDGES+255)/256,256,0,stream>>>(i_ei, i_ei + N_EDGES, ro, cursor, perm);

  const int NAGG = (N_NODES+3)/4;

  // layer 0: cew GAT (GEMM + fused s-dot via atomicAdd into sbuf)
  k_gemm_rd<1><<<MT128*1,256,0,stream>>>(xb, cewWt, i_cewB, h0, 128, 128, 1,
                                         i_cewA, nullptr, sbuf, nullptr);
  k_agg_cew<<<NAGG,256,0,stream>>>(h0, sbuf, i_cew, ro, perm, x1);

  // layer 1: GAT(128 -> 4x64) (GEMM + fused aS/aD)
  k_gemm_rd<2><<<MT128*2,256,0,stream>>>(x1, W1t, nullptr, h1, 128, 256, 2,
                                         i_aS1, i_aD1, aS, aD);
  k_agg_gat1<<<NAGG,256,0,stream>>>(h1, aS, aD, i_b1, ro, perm, x2);

  // layer 2: GAT(256 -> 4x32) (GEMM + fused aS/aD)
  k_gemm_rd<3><<<MT128*1,256,0,stream>>>(x2, W2t, nullptr, h2, 256, 128, 1,
                                         i_aS2, i_aD2, aS, aD);
  k_agg_gat2<<<NAGG,256,0,stream>>>(h2, aS, aD, i_b2, ro, perm, x3);

  // layer 3: transformer conv (fused GEMM + 4-edge-batched attention + fused final linear)
  k_gemm_qkvs<<<MT128*7,256,0,stream>>>(x3, Wcat, i_bq, i_bk, i_bv, qb, kvb, skipb);
  k_tr<<<NAGG,256,0,stream>>>(qb, kvb, skipb, i_bsk, ro, perm, i_Wf, i_bf, outf);
}